// Round 9
// baseline (436.505 us; speedup 1.0000x reference)
//
#include <hip/hip_runtime.h>
#include <hip/hip_bf16.h>

// ---------------------------------------------------------------------------
// RecurrentAttention: B=4, L=1024, D_MODEL=1024, N_HEAD=16, D_HEAD=64
// Inputs/outputs fp32; internals bf16, fp32 accumulate.
//
// ws (bf16-el units, 35.65 MB proven-safe):
//   Wb    [0, 4194304)         weights rotate -> M_xs (x-attn OutB)
//   q1q2  [4194304, 12582912)  kvs_b -> Q outputs [4096x2048] -> Wt_xp
//   Mbuf  [12582912, 16777216) kvx_b -> qs_b -> M_s -> qx_b -> M_x
//   kvpx  [16777216,+524288)   Kp [4096x64] + Vt [4][64][1024]
//   kvps  [17301504,+524288)
// d_out lo = bf16 scratch for M_sx (dead before final x_out write).
// All launches sequential on one stream -> aliasing race-free.
//
// v9 (R8 post-mortem): gemm_q/gemm_proj get the T3 "minimum 2-phase"
// double-buffer: previously gl_lds was issued then IMMEDIATELY waited
// (barrier's implicit vmcnt(0)) -> full L2 latency exposed per K-iter.
// Now: barrier -> STAGE(next tile into buf^1) -> compute buf -> loop.
// One barrier per BK=64 (16 total) and load latency hides under the
// 16-MFMA compute phase. LDS 48KB: gemm_q 3 blk/CU, proj 2 blk/CU.
// attn unchanged (proven 65.5us: swapped-QK in-reg softmax, __expf).
// ---------------------------------------------------------------------------

typedef short short8 __attribute__((ext_vector_type(8)));
typedef short short4v __attribute__((ext_vector_type(4)));
typedef float floatx4 __attribute__((ext_vector_type(4)));
typedef float floatx16 __attribute__((ext_vector_type(16)));
typedef unsigned uintx2 __attribute__((ext_vector_type(2)));

__device__ __forceinline__ float b2f(ushort h) {
    union { unsigned u; float f; } v; v.u = ((unsigned)h) << 16; return v.f;
}
__device__ __forceinline__ ushort f2bf(float f) {
    union { float f; unsigned u; } v; v.f = f;
    return (ushort)((v.u + 0x7FFFu + ((v.u >> 16) & 1u)) >> 16);
}
__device__ __forceinline__ unsigned cvt_pk_bf16(float lo, float hi) {
    unsigned r;
    asm("v_cvt_pk_bf16_f32 %0, %1, %2" : "=v"(r) : "v"(lo), "v"(hi));
    return r;
}
__device__ __forceinline__ void gl_lds16(const ushort* g, ushort* l) {
    __builtin_amdgcn_global_load_lds(
        (const __attribute__((address_space(1))) void*)g,
        (__attribute__((address_space(3))) void*)l, 16, 0, 0);
}

// ---------------------------------------------------------------------------
// Batched fp32 -> bf16 cast. grid (4096, 1, nz), block 256: 4 el/thread.
// ---------------------------------------------------------------------------
struct CB { const float* src[2]; ushort* dst[2]; };

__global__ __launch_bounds__(256) void castb(CB cb) {
    const int z = blockIdx.z;
    const float* s = cb.src[z];
    ushort* d = cb.dst[z];
    const size_t i = ((size_t)blockIdx.x * 256 + threadIdx.x) * 4;
    floatx4 f = *(const floatx4*)&s[i];
    short4v o;
#pragma unroll
    for (int k = 0; k < 4; k++) o[k] = (short)f2bf(f[k]);
    *(short4v*)&d[i] = o;
}

// ---------------------------------------------------------------------------
// Batched fp32->bf16 weight transpose: Wt[n*K+k] = bf16(W[k*N+n])
// ---------------------------------------------------------------------------
struct TB { const float* src[4]; ushort* dst[4]; int K[4]; int N[4]; };

__global__ __launch_bounds__(256) void tbatch(TB tb) {
    __shared__ float tile[32][33];
    const int wi = blockIdx.z;
    const int K = tb.K[wi], N = tb.N[wi];
    const int k0 = blockIdx.x * 32, n0 = blockIdx.y * 32;
    if (k0 >= K || n0 >= N) return;
    const float* W = tb.src[wi];
    ushort* Wt = tb.dst[wi];
    const int tx = threadIdx.x & 31, ty = threadIdx.x >> 5;
#pragma unroll
    for (int i = ty; i < 32; i += 8)
        tile[i][tx] = W[(size_t)(k0 + i) * N + n0 + tx];
    __syncthreads();
#pragma unroll
    for (int i = ty; i < 32; i += 8)
        Wt[(size_t)(n0 + i) * K + k0 + tx] = f2bf(tile[tx][i]);
}

// ---------------------------------------------------------------------------
// Q-GEMM, 128x64 tile, BK=64, 2-phase dbuf (v9):
// C = cscale*(A[4096x1024] @ Bt^T), Bt [2048][1024], C bf16 ldc=2048.
// grid (32, 32) = 1024 blocks. LDS 48KB -> 3 blk/CU.
// ---------------------------------------------------------------------------
__global__ __launch_bounds__(256) void gemm_q(
    const ushort* __restrict__ A, const ushort* __restrict__ Bt,
    ushort* __restrict__ C, float cscale)
{
    __shared__ ushort As[2][2][128 * 32];
    __shared__ ushort Bs[2][2][64 * 32];
    const int t = threadIdx.x;
    const int lane = t & 63, w = t >> 6;
    const int q = lane >> 4, li = lane & 15;
    const int rowA = blockIdx.x * 128, colB = blockIdx.y * 64;
    const int ar = rowA + w * 32 + (lane >> 2);
    const int br = colB + w * 16 + (lane >> 2);
    const int cl = (lane & 3) * 8;

    floatx4 acc[2][4];
    const floatx4 z4 = {0.f, 0.f, 0.f, 0.f};
#pragma unroll
    for (int i = 0; i < 2; i++)
#pragma unroll
        for (int j = 0; j < 4; j++) acc[i][j] = z4;

    auto stage = [&](int ph, int k0) {
        gl_lds16(A + (size_t)ar * 1024 + k0 + cl,        &As[ph][0][w * 32 * 32]);
        gl_lds16(A + (size_t)(ar + 16) * 1024 + k0 + cl, &As[ph][0][w * 32 * 32] + 16 * 32);
        gl_lds16(A + (size_t)ar * 1024 + k0 + 32 + cl,        &As[ph][1][w * 32 * 32]);
        gl_lds16(A + (size_t)(ar + 16) * 1024 + k0 + 32 + cl, &As[ph][1][w * 32 * 32] + 16 * 32);
        gl_lds16(Bt + (size_t)br * 1024 + k0 + cl,      &Bs[ph][0][w * 16 * 32]);
        gl_lds16(Bt + (size_t)br * 1024 + k0 + 32 + cl, &Bs[ph][1][w * 16 * 32]);
    };

    stage(0, 0);
    for (int it = 0; it < 16; it++) {
        const int cur = it & 1;
        __syncthreads();                       // buf[cur] loads drained here
        if (it < 15) stage(cur ^ 1, (it + 1) * 64);  // issue-early: hides under MFMA
        short8 af[2], bf[4];
#pragma unroll
        for (int ks = 0; ks < 2; ks++) {
#pragma unroll
            for (int i = 0; i < 2; i++)
                af[i] = *(const short8*)&As[cur][ks][(w * 32 + i * 16 + li) * 32 + q * 8];
#pragma unroll
            for (int j = 0; j < 4; j++)
                bf[j] = *(const short8*)&Bs[cur][ks][(j * 16 + li) * 32 + q * 8];
#pragma unroll
            for (int i = 0; i < 2; i++)
#pragma unroll
                for (int j = 0; j < 4; j++)
                    acc[i][j] = __builtin_amdgcn_mfma_f32_16x16x32_bf16(af[i], bf[j], acc[i][j], 0, 0, 0);
        }
    }
#pragma unroll
    for (int i = 0; i < 2; i++) {
        const int rowb = rowA + w * 32 + i * 16 + q * 4;
#pragma unroll
        for (int j = 0; j < 4; j++) {
            const int col = colB + j * 16 + li;
#pragma unroll
            for (int r = 0; r < 4; r++)
                C[(size_t)(rowb + r) * 2048 + col] = f2bf(acc[i][j][r] * cscale);
        }
    }
}

// ---------------------------------------------------------------------------
// KV-GEMM (z=2 batched): C = A[4096x1024] @ Bt[128][1024]^T; epilogue splits
// cols 0-63 -> Kp[row*64+col], 64-127 -> Vt[b][d][tok]. grid (32,1,2).
// ---------------------------------------------------------------------------
__global__ __launch_bounds__(256) void gemm_kv(
    const ushort* __restrict__ A0, const ushort* __restrict__ A1,
    const ushort* __restrict__ B0, const ushort* __restrict__ B1,
    ushort* __restrict__ C0, ushort* __restrict__ C1,
    ushort* __restrict__ vt0, ushort* __restrict__ vt1)
{
    __shared__ ushort As[128 * 32];
    __shared__ ushort Bs[128 * 32];
    const int z = blockIdx.z;
    const ushort* A = z ? A1 : A0;
    const ushort* Bt = z ? B1 : B0;
    ushort* Kp = z ? C1 : C0;
    ushort* vt = z ? vt1 : vt0;

    const int t = threadIdx.x;
    const int lane = t & 63, w = t >> 6;
    const int q = lane >> 4, li = lane & 15;
    const int wr = (w >> 1) * 64, wc = (w & 1) * 64;
    const int rowA = blockIdx.x * 128;
    const int ar = rowA + w * 32 + (lane >> 2);
    const int br = w * 32 + (lane >> 2);
    const int cl = (lane & 3) * 8;
    ushort* adst = &As[w * 32 * 32];
    ushort* bdst = &Bs[w * 32 * 32];

    floatx4 acc[4][4];
    const floatx4 z4 = {0.f, 0.f, 0.f, 0.f};
#pragma unroll
    for (int i = 0; i < 4; i++)
#pragma unroll
        for (int j = 0; j < 4; j++) acc[i][j] = z4;

    for (int k0 = 0; k0 < 1024; k0 += 32) {
        gl_lds16(A + (size_t)ar * 1024 + k0 + cl, adst);
        gl_lds16(A + (size_t)(ar + 16) * 1024 + k0 + cl, adst + 16 * 32);
        gl_lds16(Bt + (size_t)br * 1024 + k0 + cl, bdst);
        gl_lds16(Bt + (size_t)(br + 16) * 1024 + k0 + cl, bdst + 16 * 32);
        __syncthreads();
        short8 af[4], bf[4];
#pragma unroll
        for (int i = 0; i < 4; i++) af[i] = *(const short8*)&As[(wr + i * 16 + li) * 32 + q * 8];
#pragma unroll
        for (int j = 0; j < 4; j++) bf[j] = *(const short8*)&Bs[(wc + j * 16 + li) * 32 + q * 8];
#pragma unroll
        for (int i = 0; i < 4; i++)
#pragma unroll
            for (int j = 0; j < 4; j++)
                acc[i][j] = __builtin_amdgcn_mfma_f32_16x16x32_bf16(af[i], bf[j], acc[i][j], 0, 0, 0);
        __syncthreads();
    }
#pragma unroll
    for (int i = 0; i < 4; i++) {
        const int rowb = rowA + wr + i * 16 + q * 4;
#pragma unroll
        for (int j = 0; j < 4; j++) {
            const int col = wc + j * 16 + li;
#pragma unroll
            for (int r = 0; r < 4; r++) {
                const int row = rowb + r;
                const ushort vb = f2bf(acc[i][j][r]);
                if (col < 64) Kp[(size_t)row * 64 + col] = vb;
                else vt[((row >> 10) << 16) + ((col - 64) << 10) + (row & 1023)] = vb;
            }
        }
    }
}

// ---------------------------------------------------------------------------
// Fused concat-projection GEMM, 128x64 tile, BK=64, 2-phase dbuf (v9), K=2048:
// C = [A1|A2] @ Bt^T + bias (fp32 out). grid (32, 16) = 512 blocks = 2/CU.
// ---------------------------------------------------------------------------
__global__ __launch_bounds__(256) void gemm_proj(
    const ushort* __restrict__ A1, const ushort* __restrict__ A2,
    const ushort* __restrict__ Bt, const float* __restrict__ bias,
    float* __restrict__ C)
{
    __shared__ ushort As[2][2][128 * 32];
    __shared__ ushort Bs[2][2][64 * 32];
    const int t = threadIdx.x;
    const int lane = t & 63, w = t >> 6;
    const int q = lane >> 4, li = lane & 15;
    const int rowA = blockIdx.x * 128, colB = blockIdx.y * 64;
    const int ar = rowA + w * 32 + (lane >> 2);
    const int br = colB + w * 16 + (lane >> 2);
    const int cl = (lane & 3) * 8;

    floatx4 acc[2][4];
    const floatx4 z4 = {0.f, 0.f, 0.f, 0.f};
#pragma unroll
    for (int i = 0; i < 2; i++)
#pragma unroll
        for (int j = 0; j < 4; j++) acc[i][j] = z4;

    auto stage = [&](int ph, int k0) {
        const ushort* Ap = (k0 < 1024) ? A1 : A2;
        const int kc = k0 & 1023;
        const int koff = (k0 >= 1024) ? 64 : 0;
        const int kp0 = kc + cl;
        const int kp1 = kc + 32 + cl;
        const int ks0 = ((kp0 >> 6) << 7) + (kp0 & 63) + koff;
        const int ks1 = ((kp1 >> 6) << 7) + (kp1 & 63) + koff;
        gl_lds16(Ap + (size_t)ar * 1024 + kc + cl,        &As[ph][0][w * 32 * 32]);
        gl_lds16(Ap + (size_t)(ar + 16) * 1024 + kc + cl, &As[ph][0][w * 32 * 32] + 16 * 32);
        gl_lds16(Ap + (size_t)ar * 1024 + kc + 32 + cl,        &As[ph][1][w * 32 * 32]);
        gl_lds16(Ap + (size_t)(ar + 16) * 1024 + kc + 32 + cl, &As[ph][1][w * 32 * 32] + 16 * 32);
        gl_lds16(Bt + (size_t)br * 2048 + ks0, &Bs[ph][0][w * 16 * 32]);
        gl_lds16(Bt + (size_t)br * 2048 + ks1, &Bs[ph][1][w * 16 * 32]);
    };

    stage(0, 0);
    for (int it = 0; it < 32; it++) {
        const int cur = it & 1;
        __syncthreads();
        if (it < 31) stage(cur ^ 1, (it + 1) * 64);
        short8 af[2], bf[4];
#pragma unroll
        for (int ks = 0; ks < 2; ks++) {
#pragma unroll
            for (int i = 0; i < 2; i++)
                af[i] = *(const short8*)&As[cur][ks][(w * 32 + i * 16 + li) * 32 + q * 8];
#pragma unroll
            for (int j = 0; j < 4; j++)
                bf[j] = *(const short8*)&Bs[cur][ks][(j * 16 + li) * 32 + q * 8];
#pragma unroll
            for (int i = 0; i < 2; i++)
#pragma unroll
                for (int j = 0; j < 4; j++)
                    acc[i][j] = __builtin_amdgcn_mfma_f32_16x16x32_bf16(af[i], bf[j], acc[i][j], 0, 0, 0);
        }
    }
#pragma unroll
    for (int i = 0; i < 2; i++) {
        const int rowb = rowA + w * 32 + i * 16 + q * 4;
#pragma unroll
        for (int j = 0; j < 4; j++) {
            const int col = colB + j * 16 + li;
            const float bv = bias[col];
#pragma unroll
            for (int r = 0; r < 4; r++)
                C[(size_t)(rowb + r) * 1024 + col] = acc[i][j][r] + bv;
        }
    }
}

// ---------------------------------------------------------------------------
// Flash attention (round-5 proven config): 32x32 swapped-QK^T,
// in-register softmax, __expf value path, qscale 0.125. grid (8,16,8).
// ---------------------------------------------------------------------------
__global__ __launch_bounds__(256, 4) void attn_kernel(
    const ushort* __restrict__ Qbase,
    const ushort* __restrict__ KVa, const ushort* __restrict__ KVb,
    ushort* __restrict__ OutA, ushort* __restrict__ OutB)
{
    __shared__ ushort Kt[64 * 68];   // [key][d]
    __shared__ ushort Vt[64 * 68];   // [d][key]
    __shared__ __align__(16) float Ls[4][32];  // per-wave lsum transpose

    const int t = threadIdx.x;
    const int lane = t & 63, w = t >> 6;
    const int ql = lane & 31, hi = lane >> 5;
    const int qt = blockIdx.x, h = blockIdx.y;
    const int z = blockIdx.z, b = z >> 1, a2 = z & 1;

    const ushort* Q  = Qbase + (a2 ? 1024 : 0);
    const ushort* KV = a2 ? KVb : KVa;
    ushort* Out      = a2 ? OutB : OutA;
    const ushort* Kp = KV;
    const ushort* Vg = KV + 262144;

    const size_t qrow = (size_t)(b * 1024 + qt * 128 + w * 32 + ql);
    short8 qf[4];
#pragma unroll
    for (int dc = 0; dc < 4; dc++)
        qf[dc] = *(const short8*)&Q[qrow * 2048 + h * 64 + dc * 16 + hi * 8];

    float lsum = 0.f;
    floatx16 accO[2];
#pragma unroll
    for (int dt = 0; dt < 2; dt++)
#pragma unroll
        for (int i = 0; i < 16; i++) accO[dt][i] = 0.f;

    const int srow = t >> 2, sch = (t & 3) * 16;
    const ushort* ksrc0 = &Kp[(size_t)(b * 1024 + srow) * 64 + sch];
    const ushort* vsrc0 = &Vg[(size_t)(b * 64 + srow) * 1024 + sch];
    ushort* kdst = &Kt[srow * 68 + sch];
    ushort* vdst = &Vt[srow * 68 + sch];

    short8 kreg[2], vreg[2];
#pragma unroll
    for (int i = 0; i < 2; i++) {
        kreg[i] = *(const short8*)&ksrc0[i * 8];
        vreg[i] = *(const short8*)&vsrc0[i * 8];
    }

    for (int kt = 0; kt < 16; kt++) {
#pragma unroll
        for (int i = 0; i < 2; i++) {
            *(short8*)&kdst[i * 8] = kreg[i];
            *(short8*)&vdst[i * 8] = vreg[i];
        }
        __syncthreads();

        if (kt < 15) {
            const ushort* ksrc = ksrc0 + (size_t)(kt + 1) * 64 * 64;
            const ushort* vsrc = vsrc0 + (kt + 1) * 64;
#pragma unroll
            for (int i = 0; i < 2; i++) {
                kreg[i] = *(const short8*)&ksrc[i * 8];
                vreg[i] = *(const short8*)&vsrc[i * 8];
            }
        }

#pragma unroll
        for (int ktile = 0; ktile < 2; ktile++) {
            floatx16 S;
#pragma unroll
            for (int i = 0; i < 16; i++) S[i] = 0.f;
            __builtin_amdgcn_s_setprio(1);
#pragma unroll
            for (int dc = 0; dc < 4; dc++) {
                short8 kf = *(const short8*)&Kt[(ktile * 32 + ql) * 68 + dc * 16 + hi * 8];
                S = __builtin_amdgcn_mfma_f32_32x32x16_bf16(kf, qf[dc], S, 0, 0, 0);
            }
            __builtin_amdgcn_s_setprio(0);

            float e[16];
#pragma unroll
            for (int r = 0; r < 16; r++) e[r] = __expf(S[r]);
            float sa = (e[0] + e[1]) + (e[2] + e[3]);
            float sb = (e[4] + e[5]) + (e[6] + e[7]);
            float sc = (e[8] + e[9]) + (e[10] + e[11]);
            float sd = (e[12] + e[13]) + (e[14] + e[15]);
            lsum += (sa + sb) + (sc + sd);

#pragma unroll
            for (int p = 0; p < 2; p++) {
                unsigned cA = cvt_pk_bf16(e[8 * p + 0], e[8 * p + 1]);
                unsigned cC = cvt_pk_bf16(e[8 * p + 2], e[8 * p + 3]);
                unsigned cB = cvt_pk_bf16(e[8 * p + 4], e[8 * p + 5]);
                unsigned cD = cvt_pk_bf16(e[8 * p + 6], e[8 * p + 7]);
                uintx2 s02 = __builtin_amdgcn_permlane32_swap(cA, cB, false, false);
                uintx2 s13 = __builtin_amdgcn_permlane32_swap(cC, cD, false, false);
                union { unsigned u[4]; short8 s; } pf;
                pf.u[0] = s02[0]; pf.u[1] = s13[0];
                pf.u[2] = s02[1]; pf.u[3] = s13[1];
                const int kslot = ktile * 2 + p;
                __builtin_amdgcn_s_setprio(1);
#pragma unroll
                for (int dt = 0; dt < 2; dt++) {
                    short8 vf = *(const short8*)&Vt[(dt * 32 + ql) * 68 + kslot * 16 + hi * 8];
                    accO[dt] = __builtin_amdgcn_mfma_f32_32x32x16_bf16(pf.s, vf, accO[dt], 0, 0, 0);
                }
                __builtin_amdgcn_s_setprio(0);
            }
        }
        __syncthreads();
    }

    lsum += __shfl_xor(lsum, 32);
    Ls[w][ql] = lsum;

    const int orow0 = b * 1024 + qt * 128 + w * 32;
#pragma unroll
    for (int g = 0; g < 4; g++) {
        floatx4 L4 = *(const floatx4*)&Ls[w][g * 8 + hi * 4];
#pragma unroll
        for (int rr = 0; rr < 4; rr++) {
            const float inv = 1.f / L4[rr];
            const int row = orow0 + g * 8 + hi * 4 + rr;
#pragma unroll
            for (int dt = 0; dt < 2; dt++)
                Out[(size_t)row * 1024 + h * 64 + dt * 32 + ql] =
                    f2bf(accO[dt][g * 4 + rr] * inv);
        }
    }
}

// ---------------------------------------------------------------------------
extern "C" void kernel_launch(void* const* d_in, const int* in_sizes, int n_in,
                              void* d_out, int out_size, void* d_ws, size_t ws_size,
                              hipStream_t stream) {
    const float* qx    = (const float*)d_in[0];
    const float* kvx   = (const float*)d_in[1];
    const float* qs    = (const float*)d_in[2];
    const float* kvs   = (const float*)d_in[3];
    const float* w_qx1 = (const float*)d_in[4];
    const float* w_qs1 = (const float*)d_in[5];
    const float* w_qx2 = (const float*)d_in[6];
    const float* w_qs2 = (const float*)d_in[7];
    const float* w_kvx = (const float*)d_in[8];
    const float* w_kvs = (const float*)d_in[9];
    const float* w_xp  = (const float*)d_in[10];
    const float* b_xp  = (const float*)d_in[11];
    const float* w_sp  = (const float*)d_in[12];
    const float* b_sp  = (const float*)d_in[13];
    float* out = (float*)d_out;
    (void)ws_size; (void)in_sizes; (void)n_in; (void)out_size;

    ushort* ws   = (ushort*)d_ws;
    ushort* Wb   = ws;
    ushort* q1q2 = ws + 4194304;
    ushort* Mbuf = ws + 12582912;
    ushort* kvpx = ws + 16777216;
    ushort* kvps = ws + 17301504;

    // 1) cast kv activations: kvx_b -> Mbuf, kvs_b -> q1q2 (both dead regions)
    CB c1; c1.src[0] = kvx; c1.dst[0] = Mbuf; c1.src[1] = kvs; c1.dst[1] = q1q2;
    castb<<<dim3(4096, 1, 2), 256, 0, stream>>>(c1);

    // 2) transpose kv + s-path Q weights into Wb
    TB tb1;
    tb1.src[0] = w_kvx; tb1.dst[0] = Wb;           tb1.K[0] = 1024; tb1.N[0] = 128;
    tb1.src[1] = w_kvs; tb1.dst[1] = Wb + 131072;  tb1.K[1] = 1024; tb1.N[1] = 128;
    tb1.src[2] = w_qs1; tb1.dst[2] = Wb + 262144;  tb1.K[2] = 1024; tb1.N[2] = 1024;
    tb1.src[3] = w_qs2; tb1.dst[3] = Wb + 1310720; tb1.K[3] = 1024; tb1.N[3] = 1024;
    tbatch<<<dim3(32, 32, 4), 256, 0, stream>>>(tb1);

    // 3) kv projections (z=2): K->Kp, V->Vt
    gemm_kv<<<dim3(32, 1, 2), 256, 0, stream>>>(
        Mbuf, q1q2, Wb, Wb + 131072, kvpx, kvps, kvpx + 262144, kvps + 262144);

    // 4) cast qs -> Mbuf (kvx_b dead)
    CB c2; c2.src[0] = qs; c2.dst[0] = Mbuf; c2.src[1] = qs; c2.dst[1] = Mbuf;
    castb<<<dim3(4096, 1, 1), 256, 0, stream>>>(c2);

    // 5) s-path Q GEMM: q1s|q2s -> q1q2 (kvs_b dead), scale 1/8 folded
    gemm_q<<<dim3(32, 32), 256, 0, stream>>>(Mbuf, Wb + 262144, q1q2, 0.125f);

    // 6) s attention: M_s -> Mbuf (qs_b dead), M_sx -> d_out lo (bf16 scratch)
    attn_kernel<<<dim3(8, 16, 8), 256, 0, stream>>>(q1q2, kvps, kvpx, Mbuf, (ushort*)out);

    // 7) transpose sp + x-path Q weights (Wt_kv/Wt_qs dead)
    TB tb2;
    tb2.src[0] = w_sp;  tb2.dst[0] = Wb;           tb2.K[0] = 2048; tb2.N[0] = 1024;
    tb2.src[1] = w_qx1; tb2.dst[1] = Wb + 2097152; tb2.K[1] = 1024; tb2.N[1] = 1024;
    tb2.src[2] = w_qx2; tb2.dst[2] = Wb + 3145728; tb2.K[2] = 1024; tb2.N[2] = 1024;
    tb2.src[3] = w_sp;  tb2.dst[3] = Wb;           tb2.K[3] = 0;    tb2.N[3] = 0;
    tbatch<<<dim3(64, 32, 3), 256, 0, stream>>>(tb2);

    // 8) s_out = [M_sx | M_s] @ Wsp^T + b_sp -> d_out hi (fp32)
    gemm_proj<<<dim3(32, 16), 256, 0, stream>>>((ushort*)out, Mbuf, Wb, b_sp, out + 4194304);

    // 9) cast qx -> Mbuf (M_s dead)
    CB c3; c3.src[0] = qx; c3.dst[0] = Mbuf; c3.src[1] = qx; c3.dst[1] = Mbuf;
    castb<<<dim3(4096, 1, 1), 256, 0, stream>>>(c3);

    // 10) x-path Q GEMM -> q1q2 (dead after s-attn)
    gemm_q<<<dim3(32, 32), 256, 0, stream>>>(Mbuf, Wb + 2097152, q1q2, 0.125f);

    // 11) x attention: M_x -> Mbuf (qx_b dead), M_xs -> Wb (weights dead)
    attn_kernel<<<dim3(8, 16, 8), 256, 0, stream>>>(q1q2, kvpx, kvps, Mbuf, Wb);

    // 12) transpose xp -> q1q2 (dead after x-attn)
    TB tb3;
    tb3.src[0] = w_xp; tb3.dst[0] = q1q2; tb3.K[0] = 2048; tb3.N[0] = 1024;
    tb3.src[1] = w_xp; tb3.dst[1] = q1q2; tb3.K[1] = 0;    tb3.N[1] = 0;
    tb3.src[2] = w_xp; tb3.dst[2] = q1q2; tb3.K[2] = 0;    tb3.N[2] = 0;
    tb3.src[3] = w_xp; tb3.dst[3] = q1q2; tb3.K[3] = 0;    tb3.N[3] = 0;
    tbatch<<<dim3(64, 32, 1), 256, 0, stream>>>(tb3);

    // 13) x_out = [M_xs | M_x] @ Wxp^T + b_xp -> d_out lo (M_sx scratch dead)
    gemm_proj<<<dim3(32, 16), 256, 0, stream>>>(Wb, Mbuf, q1q2, b_xp, out);
}

// Round 10
// 420.676 us; speedup vs baseline: 1.0376x; 1.0376x over previous
//
#include <hip/hip_runtime.h>
#include <hip/hip_bf16.h>

// ---------------------------------------------------------------------------
// RecurrentAttention: B=4, L=1024, D_MODEL=1024, N_HEAD=16, D_HEAD=64
// Inputs/outputs fp32; internals bf16, fp32 accumulate.
//
// ws (bf16-el units, 35.65 MB proven-safe):
//   Wb    [0, 4194304)         weights rotate -> M_xs (x-attn OutB)
//   q1q2  [4194304, 12582912)  kvs_b -> Q outputs [4096x2048] -> Wt_xp
//   Mbuf  [12582912, 16777216) kvx_b -> qs_b -> M_s -> qx_b -> M_x
//   kvpx  [16777216,+524288)   Kp [4096x64] + Vt [4][64][1024]
//   kvps  [17301504,+524288)
// d_out lo = bf16 scratch for M_sx (dead before final x_out write).
// All launches sequential on one stream -> aliasing race-free.
//
// v10 (R9 post-mortem): explicit 2-phase dbuf REGRESSED (+19us) — barriers
// drain vmcnt(0) so cross-barrier prefetch can't live, and 48KB LDS cut
// gemm_q 4->3 blk/CU (m99/m100/m114: implicit multi-block overlap IS the
// pipeline). Reverted to R8 single-buffer BK=64 twin.
// gemm_proj additionally retiled 128x64 -> 64x64 with BK=128 (4 subtiles):
// keeps 16 MFMA/barrier-pair, grid (64,16)=1024 blocks = 4 blk/CU (was 2),
// LDS 32KB. attn unchanged (proven 64.5us).
// ---------------------------------------------------------------------------

typedef short short8 __attribute__((ext_vector_type(8)));
typedef short short4v __attribute__((ext_vector_type(4)));
typedef float floatx4 __attribute__((ext_vector_type(4)));
typedef float floatx16 __attribute__((ext_vector_type(16)));
typedef unsigned uintx2 __attribute__((ext_vector_type(2)));

__device__ __forceinline__ float b2f(ushort h) {
    union { unsigned u; float f; } v; v.u = ((unsigned)h) << 16; return v.f;
}
__device__ __forceinline__ ushort f2bf(float f) {
    union { float f; unsigned u; } v; v.f = f;
    return (ushort)((v.u + 0x7FFFu + ((v.u >> 16) & 1u)) >> 16);
}
__device__ __forceinline__ unsigned cvt_pk_bf16(float lo, float hi) {
    unsigned r;
    asm("v_cvt_pk_bf16_f32 %0, %1, %2" : "=v"(r) : "v"(lo), "v"(hi));
    return r;
}
__device__ __forceinline__ void gl_lds16(const ushort* g, ushort* l) {
    __builtin_amdgcn_global_load_lds(
        (const __attribute__((address_space(1))) void*)g,
        (__attribute__((address_space(3))) void*)l, 16, 0, 0);
}

// ---------------------------------------------------------------------------
// Batched fp32 -> bf16 cast. grid (4096, 1, nz), block 256: 4 el/thread.
// ---------------------------------------------------------------------------
struct CB { const float* src[2]; ushort* dst[2]; };

__global__ __launch_bounds__(256) void castb(CB cb) {
    const int z = blockIdx.z;
    const float* s = cb.src[z];
    ushort* d = cb.dst[z];
    const size_t i = ((size_t)blockIdx.x * 256 + threadIdx.x) * 4;
    floatx4 f = *(const floatx4*)&s[i];
    short4v o;
#pragma unroll
    for (int k = 0; k < 4; k++) o[k] = (short)f2bf(f[k]);
    *(short4v*)&d[i] = o;
}

// ---------------------------------------------------------------------------
// Batched fp32->bf16 weight transpose: Wt[n*K+k] = bf16(W[k*N+n])
// ---------------------------------------------------------------------------
struct TB { const float* src[4]; ushort* dst[4]; int K[4]; int N[4]; };

__global__ __launch_bounds__(256) void tbatch(TB tb) {
    __shared__ float tile[32][33];
    const int wi = blockIdx.z;
    const int K = tb.K[wi], N = tb.N[wi];
    const int k0 = blockIdx.x * 32, n0 = blockIdx.y * 32;
    if (k0 >= K || n0 >= N) return;
    const float* W = tb.src[wi];
    ushort* Wt = tb.dst[wi];
    const int tx = threadIdx.x & 31, ty = threadIdx.x >> 5;
#pragma unroll
    for (int i = ty; i < 32; i += 8)
        tile[i][tx] = W[(size_t)(k0 + i) * N + n0 + tx];
    __syncthreads();
#pragma unroll
    for (int i = ty; i < 32; i += 8)
        Wt[(size_t)(n0 + i) * K + k0 + tx] = f2bf(tile[tx][i]);
}

// ---------------------------------------------------------------------------
// Q-GEMM, 128x64 tile, BK=64 (R8 proven): C = cscale*(A[4096x1024] @ Bt^T),
// Bt [2048][1024], C bf16 ldc=2048. grid (32, 32) = 1024 blocks = 4/CU.
// Twin K=32 sub-tiles per barrier pair -> 16 MFMA / 2 barriers. LDS 24KB.
// ---------------------------------------------------------------------------
__global__ __launch_bounds__(256) void gemm_q(
    const ushort* __restrict__ A, const ushort* __restrict__ Bt,
    ushort* __restrict__ C, float cscale)
{
    __shared__ ushort As0[128 * 32];
    __shared__ ushort As1[128 * 32];
    __shared__ ushort Bs0[64 * 32];
    __shared__ ushort Bs1[64 * 32];
    const int t = threadIdx.x;
    const int lane = t & 63, w = t >> 6;
    const int q = lane >> 4, li = lane & 15;
    const int rowA = blockIdx.x * 128, colB = blockIdx.y * 64;
    const int ar = rowA + w * 32 + (lane >> 2);
    const int br = colB + w * 16 + (lane >> 2);
    const int cl = (lane & 3) * 8;
    ushort* adst0 = &As0[w * 32 * 32];
    ushort* adst1 = &As1[w * 32 * 32];
    ushort* bdst0 = &Bs0[w * 16 * 32];
    ushort* bdst1 = &Bs1[w * 16 * 32];

    floatx4 acc[2][4];
    const floatx4 z4 = {0.f, 0.f, 0.f, 0.f};
#pragma unroll
    for (int i = 0; i < 2; i++)
#pragma unroll
        for (int j = 0; j < 4; j++) acc[i][j] = z4;

    for (int k0 = 0; k0 < 1024; k0 += 64) {
        gl_lds16(A + (size_t)ar * 1024 + k0 + cl, adst0);
        gl_lds16(A + (size_t)(ar + 16) * 1024 + k0 + cl, adst0 + 16 * 32);
        gl_lds16(A + (size_t)ar * 1024 + k0 + 32 + cl, adst1);
        gl_lds16(A + (size_t)(ar + 16) * 1024 + k0 + 32 + cl, adst1 + 16 * 32);
        gl_lds16(Bt + (size_t)br * 1024 + k0 + cl, bdst0);
        gl_lds16(Bt + (size_t)br * 1024 + k0 + 32 + cl, bdst1);
        __syncthreads();
        short8 af[2], bf[4];
#pragma unroll
        for (int i = 0; i < 2; i++) af[i] = *(const short8*)&As0[(w * 32 + i * 16 + li) * 32 + q * 8];
#pragma unroll
        for (int j = 0; j < 4; j++) bf[j] = *(const short8*)&Bs0[(j * 16 + li) * 32 + q * 8];
#pragma unroll
        for (int i = 0; i < 2; i++)
#pragma unroll
            for (int j = 0; j < 4; j++)
                acc[i][j] = __builtin_amdgcn_mfma_f32_16x16x32_bf16(af[i], bf[j], acc[i][j], 0, 0, 0);
#pragma unroll
        for (int i = 0; i < 2; i++) af[i] = *(const short8*)&As1[(w * 32 + i * 16 + li) * 32 + q * 8];
#pragma unroll
        for (int j = 0; j < 4; j++) bf[j] = *(const short8*)&Bs1[(j * 16 + li) * 32 + q * 8];
#pragma unroll
        for (int i = 0; i < 2; i++)
#pragma unroll
            for (int j = 0; j < 4; j++)
                acc[i][j] = __builtin_amdgcn_mfma_f32_16x16x32_bf16(af[i], bf[j], acc[i][j], 0, 0, 0);
        __syncthreads();
    }
#pragma unroll
    for (int i = 0; i < 2; i++) {
        const int rowb = rowA + w * 32 + i * 16 + q * 4;
#pragma unroll
        for (int j = 0; j < 4; j++) {
            const int col = colB + j * 16 + li;
#pragma unroll
            for (int r = 0; r < 4; r++)
                C[(size_t)(rowb + r) * 2048 + col] = f2bf(acc[i][j][r] * cscale);
        }
    }
}

// ---------------------------------------------------------------------------
// KV-GEMM (z=2 batched): C = A[4096x1024] @ Bt[128][1024]^T; epilogue splits
// cols 0-63 -> Kp[row*64+col], 64-127 -> Vt[b][d][tok]. grid (32,1,2).
// ---------------------------------------------------------------------------
__global__ __launch_bounds__(256) void gemm_kv(
    const ushort* __restrict__ A0, const ushort* __restrict__ A1,
    const ushort* __restrict__ B0, const ushort* __restrict__ B1,
    ushort* __restrict__ C0, ushort* __restrict__ C1,
    ushort* __restrict__ vt0, ushort* __restrict__ vt1)
{
    __shared__ ushort As[128 * 32];
    __shared__ ushort Bs[128 * 32];
    const int z = blockIdx.z;
    const ushort* A = z ? A1 : A0;
    const ushort* Bt = z ? B1 : B0;
    ushort* Kp = z ? C1 : C0;
    ushort* vt = z ? vt1 : vt0;

    const int t = threadIdx.x;
    const int lane = t & 63, w = t >> 6;
    const int q = lane >> 4, li = lane & 15;
    const int wr = (w >> 1) * 64, wc = (w & 1) * 64;
    const int rowA = blockIdx.x * 128;
    const int ar = rowA + w * 32 + (lane >> 2);
    const int br = w * 32 + (lane >> 2);
    const int cl = (lane & 3) * 8;
    ushort* adst = &As[w * 32 * 32];
    ushort* bdst = &Bs[w * 32 * 32];

    floatx4 acc[4][4];
    const floatx4 z4 = {0.f, 0.f, 0.f, 0.f};
#pragma unroll
    for (int i = 0; i < 4; i++)
#pragma unroll
        for (int j = 0; j < 4; j++) acc[i][j] = z4;

    for (int k0 = 0; k0 < 1024; k0 += 32) {
        gl_lds16(A + (size_t)ar * 1024 + k0 + cl, adst);
        gl_lds16(A + (size_t)(ar + 16) * 1024 + k0 + cl, adst + 16 * 32);
        gl_lds16(Bt + (size_t)br * 1024 + k0 + cl, bdst);
        gl_lds16(Bt + (size_t)(br + 16) * 1024 + k0 + cl, bdst + 16 * 32);
        __syncthreads();
        short8 af[4], bf[4];
#pragma unroll
        for (int i = 0; i < 4; i++) af[i] = *(const short8*)&As[(wr + i * 16 + li) * 32 + q * 8];
#pragma unroll
        for (int j = 0; j < 4; j++) bf[j] = *(const short8*)&Bs[(wc + j * 16 + li) * 32 + q * 8];
#pragma unroll
        for (int i = 0; i < 4; i++)
#pragma unroll
            for (int j = 0; j < 4; j++)
                acc[i][j] = __builtin_amdgcn_mfma_f32_16x16x32_bf16(af[i], bf[j], acc[i][j], 0, 0, 0);
        __syncthreads();
    }
#pragma unroll
    for (int i = 0; i < 4; i++) {
        const int rowb = rowA + wr + i * 16 + q * 4;
#pragma unroll
        for (int j = 0; j < 4; j++) {
            const int col = wc + j * 16 + li;
#pragma unroll
            for (int r = 0; r < 4; r++) {
                const int row = rowb + r;
                const ushort vb = f2bf(acc[i][j][r]);
                if (col < 64) Kp[(size_t)row * 64 + col] = vb;
                else vt[((row >> 10) << 16) + ((col - 64) << 10) + (row & 1023)] = vb;
            }
        }
    }
}

// ---------------------------------------------------------------------------
// Fused concat-projection GEMM, 64x64 tile, BK=128 (v10), K=2048:
// C = [A1|A2] @ Bt^T + bias (fp32 out). 4 K=32 sub-tiles per barrier pair
// -> 16 MFMA / 2 barriers. grid (64, 16) = 1024 blocks = 4/CU. LDS 32KB.
// ---------------------------------------------------------------------------
__global__ __launch_bounds__(256) void gemm_proj(
    const ushort* __restrict__ A1, const ushort* __restrict__ A2,
    const ushort* __restrict__ Bt, const float* __restrict__ bias,
    float* __restrict__ C)
{
    __shared__ ushort As[4][64 * 32];
    __shared__ ushort Bs[4][64 * 32];
    const int t = threadIdx.x;
    const int lane = t & 63, w = t >> 6;
    const int q = lane >> 4, li = lane & 15;
    const int wr = (w >> 1) * 32, wc = (w & 1) * 32;
    const int rowA = blockIdx.x * 64, colB = blockIdx.y * 64;
    const int ar = rowA + w * 16 + (lane >> 2);
    const int br = colB + w * 16 + (lane >> 2);
    const int cl = (lane & 3) * 8;

    floatx4 acc[2][2];
    const floatx4 z4 = {0.f, 0.f, 0.f, 0.f};
#pragma unroll
    for (int i = 0; i < 2; i++)
#pragma unroll
        for (int j = 0; j < 2; j++) acc[i][j] = z4;

    for (int k0 = 0; k0 < 2048; k0 += 128) {
        const ushort* Ap = (k0 < 1024) ? A1 : A2;
        const int kc = k0 & 1023;
        const int koff = (k0 >= 1024) ? 64 : 0;
#pragma unroll
        for (int s = 0; s < 4; s++) {
            const int kp = kc + s * 32 + cl;
            const int ks = ((kp >> 6) << 7) + (kp & 63) + koff;
            gl_lds16(Ap + (size_t)ar * 1024 + kc + s * 32 + cl, &As[s][w * 16 * 32]);
            gl_lds16(Bt + (size_t)br * 2048 + ks, &Bs[s][w * 16 * 32]);
        }
        __syncthreads();
        short8 af[2], bf[2];
#pragma unroll
        for (int s = 0; s < 4; s++) {
#pragma unroll
            for (int i = 0; i < 2; i++)
                af[i] = *(const short8*)&As[s][(wr + i * 16 + li) * 32 + q * 8];
#pragma unroll
            for (int j = 0; j < 2; j++)
                bf[j] = *(const short8*)&Bs[s][(wc + j * 16 + li) * 32 + q * 8];
#pragma unroll
            for (int i = 0; i < 2; i++)
#pragma unroll
                for (int j = 0; j < 2; j++)
                    acc[i][j] = __builtin_amdgcn_mfma_f32_16x16x32_bf16(af[i], bf[j], acc[i][j], 0, 0, 0);
        }
        __syncthreads();
    }
#pragma unroll
    for (int i = 0; i < 2; i++) {
        const int rowb = rowA + wr + i * 16 + q * 4;
#pragma unroll
        for (int j = 0; j < 2; j++) {
            const int col = colB + wc + j * 16 + li;
            const float bv = bias[col];
#pragma unroll
            for (int r = 0; r < 4; r++)
                C[(size_t)(rowb + r) * 1024 + col] = acc[i][j][r] + bv;
        }
    }
}

// ---------------------------------------------------------------------------
// Flash attention (round-5 proven config): 32x32 swapped-QK^T,
// in-register softmax, __expf value path, qscale 0.125. grid (8,16,8).
// ---------------------------------------------------------------------------
__global__ __launch_bounds__(256, 4) void attn_kernel(
    const ushort* __restrict__ Qbase,
    const ushort* __restrict__ KVa, const ushort* __restrict__ KVb,
    ushort* __restrict__ OutA, ushort* __restrict__ OutB)
{
    __shared__ ushort Kt[64 * 68];   // [key][d]
    __shared__ ushort Vt[64 * 68];   // [d][key]
    __shared__ __align__(16) float Ls[4][32];  // per-wave lsum transpose

    const int t = threadIdx.x;
    const int lane = t & 63, w = t >> 6;
    const int ql = lane & 31, hi = lane >> 5;
    const int qt = blockIdx.x, h = blockIdx.y;
    const int z = blockIdx.z, b = z >> 1, a2 = z & 1;

    const ushort* Q  = Qbase + (a2 ? 1024 : 0);
    const ushort* KV = a2 ? KVb : KVa;
    ushort* Out      = a2 ? OutB : OutA;
    const ushort* Kp = KV;
    const ushort* Vg = KV + 262144;

    const size_t qrow = (size_t)(b * 1024 + qt * 128 + w * 32 + ql);
    short8 qf[4];
#pragma unroll
    for (int dc = 0; dc < 4; dc++)
        qf[dc] = *(const short8*)&Q[qrow * 2048 + h * 64 + dc * 16 + hi * 8];

    float lsum = 0.f;
    floatx16 accO[2];
#pragma unroll
    for (int dt = 0; dt < 2; dt++)
#pragma unroll
        for (int i = 0; i < 16; i++) accO[dt][i] = 0.f;

    const int srow = t >> 2, sch = (t & 3) * 16;
    const ushort* ksrc0 = &Kp[(size_t)(b * 1024 + srow) * 64 + sch];
    const ushort* vsrc0 = &Vg[(size_t)(b * 64 + srow) * 1024 + sch];
    ushort* kdst = &Kt[srow * 68 + sch];
    ushort* vdst = &Vt[srow * 68 + sch];

    short8 kreg[2], vreg[2];
#pragma unroll
    for (int i = 0; i < 2; i++) {
        kreg[i] = *(const short8*)&ksrc0[i * 8];
        vreg[i] = *(const short8*)&vsrc0[i * 8];
    }

    for (int kt = 0; kt < 16; kt++) {
#pragma unroll
        for (int i = 0; i < 2; i++) {
            *(short8*)&kdst[i * 8] = kreg[i];
            *(short8*)&vdst[i * 8] = vreg[i];
        }
        __syncthreads();

        if (kt < 15) {
            const ushort* ksrc = ksrc0 + (size_t)(kt + 1) * 64 * 64;
            const ushort* vsrc = vsrc0 + (kt + 1) * 64;
#pragma unroll
            for (int i = 0; i < 2; i++) {
                kreg[i] = *(const short8*)&ksrc[i * 8];
                vreg[i] = *(const short8*)&vsrc[i * 8];
            }
        }

#pragma unroll
        for (int ktile = 0; ktile < 2; ktile++) {
            floatx16 S;
#pragma unroll
            for (int i = 0; i < 16; i++) S[i] = 0.f;
            __builtin_amdgcn_s_setprio(1);
#pragma unroll
            for (int dc = 0; dc < 4; dc++) {
                short8 kf = *(const short8*)&Kt[(ktile * 32 + ql) * 68 + dc * 16 + hi * 8];
                S = __builtin_amdgcn_mfma_f32_32x32x16_bf16(kf, qf[dc], S, 0, 0, 0);
            }
            __builtin_amdgcn_s_setprio(0);

            float e[16];
#pragma unroll
            for (int r = 0; r < 16; r++) e[r] = __expf(S[r]);
            float sa = (e[0] + e[1]) + (e[2] + e[3]);
            float sb = (e[4] + e[5]) + (e[6] + e[7]);
            float sc = (e[8] + e[9]) + (e[10] + e[11]);
            float sd = (e[12] + e[13]) + (e[14] + e[15]);
            lsum += (sa + sb) + (sc + sd);

#pragma unroll
            for (int p = 0; p < 2; p++) {
                unsigned cA = cvt_pk_bf16(e[8 * p + 0], e[8 * p + 1]);
                unsigned cC = cvt_pk_bf16(e[8 * p + 2], e[8 * p + 3]);
                unsigned cB = cvt_pk_bf16(e[8 * p + 4], e[8 * p + 5]);
                unsigned cD = cvt_pk_bf16(e[8 * p + 6], e[8 * p + 7]);
                uintx2 s02 = __builtin_amdgcn_permlane32_swap(cA, cB, false, false);
                uintx2 s13 = __builtin_amdgcn_permlane32_swap(cC, cD, false, false);
                union { unsigned u[4]; short8 s; } pf;
                pf.u[0] = s02[0]; pf.u[1] = s13[0];
                pf.u[2] = s02[1]; pf.u[3] = s13[1];
                const int kslot = ktile * 2 + p;
                __builtin_amdgcn_s_setprio(1);
#pragma unroll
                for (int dt = 0; dt < 2; dt++) {
                    short8 vf = *(const short8*)&Vt[(dt * 32 + ql) * 68 + kslot * 16 + hi * 8];
                    accO[dt] = __builtin_amdgcn_mfma_f32_32x32x16_bf16(pf.s, vf, accO[dt], 0, 0, 0);
                }
                __builtin_amdgcn_s_setprio(0);
            }
        }
        __syncthreads();
    }

    lsum += __shfl_xor(lsum, 32);
    Ls[w][ql] = lsum;

    const int orow0 = b * 1024 + qt * 128 + w * 32;
#pragma unroll
    for (int g = 0; g < 4; g++) {
        floatx4 L4 = *(const floatx4*)&Ls[w][g * 8 + hi * 4];
#pragma unroll
        for (int rr = 0; rr < 4; rr++) {
            const float inv = 1.f / L4[rr];
            const int row = orow0 + g * 8 + hi * 4 + rr;
#pragma unroll
            for (int dt = 0; dt < 2; dt++)
                Out[(size_t)row * 1024 + h * 64 + dt * 32 + ql] =
                    f2bf(accO[dt][g * 4 + rr] * inv);
        }
    }
}

// ---------------------------------------------------------------------------
extern "C" void kernel_launch(void* const* d_in, const int* in_sizes, int n_in,
                              void* d_out, int out_size, void* d_ws, size_t ws_size,
                              hipStream_t stream) {
    const float* qx    = (const float*)d_in[0];
    const float* kvx   = (const float*)d_in[1];
    const float* qs    = (const float*)d_in[2];
    const float* kvs   = (const float*)d_in[3];
    const float* w_qx1 = (const float*)d_in[4];
    const float* w_qs1 = (const float*)d_in[5];
    const float* w_qx2 = (const float*)d_in[6];
    const float* w_qs2 = (const float*)d_in[7];
    const float* w_kvx = (const float*)d_in[8];
    const float* w_kvs = (const float*)d_in[9];
    const float* w_xp  = (const float*)d_in[10];
    const float* b_xp  = (const float*)d_in[11];
    const float* w_sp  = (const float*)d_in[12];
    const float* b_sp  = (const float*)d_in[13];
    float* out = (float*)d_out;
    (void)ws_size; (void)in_sizes; (void)n_in; (void)out_size;

    ushort* ws   = (ushort*)d_ws;
    ushort* Wb   = ws;
    ushort* q1q2 = ws + 4194304;
    ushort* Mbuf = ws + 12582912;
    ushort* kvpx = ws + 16777216;
    ushort* kvps = ws + 17301504;

    // 1) cast kv activations: kvx_b -> Mbuf, kvs_b -> q1q2 (both dead regions)
    CB c1; c1.src[0] = kvx; c1.dst[0] = Mbuf; c1.src[1] = kvs; c1.dst[1] = q1q2;
    castb<<<dim3(4096, 1, 2), 256, 0, stream>>>(c1);

    // 2) transpose kv + s-path Q weights into Wb
    TB tb1;
    tb1.src[0] = w_kvx; tb1.dst[0] = Wb;           tb1.K[0] = 1024; tb1.N[0] = 128;
    tb1.src[1] = w_kvs; tb1.dst[1] = Wb + 131072;  tb1.K[1] = 1024; tb1.N[1] = 128;
    tb1.src[2] = w_qs1; tb1.dst[2] = Wb + 262144;  tb1.K[2] = 1024; tb1.N[2] = 1024;
    tb1.src[3] = w_qs2; tb1.dst[3] = Wb + 1310720; tb1.K[3] = 1024; tb1.N[3] = 1024;
    tbatch<<<dim3(32, 32, 4), 256, 0, stream>>>(tb1);

    // 3) kv projections (z=2): K->Kp, V->Vt
    gemm_kv<<<dim3(32, 1, 2), 256, 0, stream>>>(
        Mbuf, q1q2, Wb, Wb + 131072, kvpx, kvps, kvpx + 262144, kvps + 262144);

    // 4) cast qs -> Mbuf (kvx_b dead)
    CB c2; c2.src[0] = qs; c2.dst[0] = Mbuf; c2.src[1] = qs; c2.dst[1] = Mbuf;
    castb<<<dim3(4096, 1, 1), 256, 0, stream>>>(c2);

    // 5) s-path Q GEMM: q1s|q2s -> q1q2 (kvs_b dead), scale 1/8 folded
    gemm_q<<<dim3(32, 32), 256, 0, stream>>>(Mbuf, Wb + 262144, q1q2, 0.125f);

    // 6) s attention: M_s -> Mbuf (qs_b dead), M_sx -> d_out lo (bf16 scratch)
    attn_kernel<<<dim3(8, 16, 8), 256, 0, stream>>>(q1q2, kvps, kvpx, Mbuf, (ushort*)out);

    // 7) transpose sp + x-path Q weights (Wt_kv/Wt_qs dead)
    TB tb2;
    tb2.src[0] = w_sp;  tb2.dst[0] = Wb;           tb2.K[0] = 2048; tb2.N[0] = 1024;
    tb2.src[1] = w_qx1; tb2.dst[1] = Wb + 2097152; tb2.K[1] = 1024; tb2.N[1] = 1024;
    tb2.src[2] = w_qx2; tb2.dst[2] = Wb + 3145728; tb2.K[2] = 1024; tb2.N[2] = 1024;
    tb2.src[3] = w_sp;  tb2.dst[3] = Wb;           tb2.K[3] = 0;    tb2.N[3] = 0;
    tbatch<<<dim3(64, 32, 3), 256, 0, stream>>>(tb2);

    // 8) s_out = [M_sx | M_s] @ Wsp^T + b_sp -> d_out hi (fp32)
    gemm_proj<<<dim3(64, 16), 256, 0, stream>>>((ushort*)out, Mbuf, Wb, b_sp, out + 4194304);

    // 9) cast qx -> Mbuf (M_s dead)
    CB c3; c3.src[0] = qx; c3.dst[0] = Mbuf; c3.src[1] = qx; c3.dst[1] = Mbuf;
    castb<<<dim3(4096, 1, 1), 256, 0, stream>>>(c3);

    // 10) x-path Q GEMM -> q1q2 (dead after s-attn)
    gemm_q<<<dim3(32, 32), 256, 0, stream>>>(Mbuf, Wb + 2097152, q1q2, 0.125f);

    // 11) x attention: M_x -> Mbuf (qx_b dead), M_xs -> Wb (weights dead)
    attn_kernel<<<dim3(8, 16, 8), 256, 0, stream>>>(q1q2, kvpx, kvps, Mbuf, Wb);

    // 12) transpose xp -> q1q2 (dead after x-attn)
    TB tb3;
    tb3.src[0] = w_xp; tb3.dst[0] = q1q2; tb3.K[0] = 2048; tb3.N[0] = 1024;
    tb3.src[1] = w_xp; tb3.dst[1] = q1q2; tb3.K[1] = 0;    tb3.N[1] = 0;
    tb3.src[2] = w_xp; tb3.dst[2] = q1q2; tb3.K[2] = 0;    tb3.N[2] = 0;
    tb3.src[3] = w_xp; tb3.dst[3] = q1q2; tb3.K[3] = 0;    tb3.N[3] = 0;
    tbatch<<<dim3(64, 32, 1), 256, 0, stream>>>(tb3);

    // 13) x_out = [M_xs | M_x] @ Wxp^T + b_xp -> d_out lo (M_sx scratch dead)
    gemm_proj<<<dim3(64, 16), 256, 0, stream>>>(Wb, Mbuf, q1q2, b_xp, out);
}

// Round 11
// 420.568 us; speedup vs baseline: 1.0379x; 1.0003x over previous
//
#include <hip/hip_runtime.h>
#include <hip/hip_bf16.h>

// ---------------------------------------------------------------------------
// RecurrentAttention: B=4, L=1024, D_MODEL=1024, N_HEAD=16, D_HEAD=64
// Inputs/outputs fp32; internals bf16, fp32 accumulate.
//
// ws (bf16-el units, 35.65 MB proven-safe):
//   Wb    [0, 4194304)         weights rotate -> M_xs (x-attn OutB)
//   q1q2  [4194304, 12582912)  kvs_b -> Q outputs [4096x2048] -> Wt_xp
//   Mbuf  [12582912, 16777216) kvx_b -> qs_b -> M_s -> qx_b -> M_x
//   kvpx  [16777216,+524288)   Kp [4096x64] + Vt [4][64][1024]
//   kvps  [17301504,+524288)
// d_out lo = bf16 scratch for M_sx (dead before final x_out write).
// All launches sequential on one stream -> aliasing race-free.
//
// v11 (R10 post-mortem): 64x64 proj retile was neutral-negative (B-panel
// traffic 2x, intensity down) -> gemm_proj reverted to R8-proven 128x64
// BK=64 twin (grid 32x16). GEMM pool pinned ~290us across 4 structures ->
// structural floor; round spent on attn instead:
//   attn v7: double-buffered K/V LDS (2x17.4KB, 35.3KB total — still
//   4 blk/CU = grid cap). ONE barrier per kt-iter (was 2): barrier ->
//   write regs(kt+1)->buf[cur^1] overlapped with compute buf[cur].
//   Value path unchanged (__expf, qsc 0.125, swapped-QK in-reg softmax).
// ---------------------------------------------------------------------------

typedef short short8 __attribute__((ext_vector_type(8)));
typedef short short4v __attribute__((ext_vector_type(4)));
typedef float floatx4 __attribute__((ext_vector_type(4)));
typedef float floatx16 __attribute__((ext_vector_type(16)));
typedef unsigned uintx2 __attribute__((ext_vector_type(2)));

__device__ __forceinline__ float b2f(ushort h) {
    union { unsigned u; float f; } v; v.u = ((unsigned)h) << 16; return v.f;
}
__device__ __forceinline__ ushort f2bf(float f) {
    union { float f; unsigned u; } v; v.f = f;
    return (ushort)((v.u + 0x7FFFu + ((v.u >> 16) & 1u)) >> 16);
}
__device__ __forceinline__ unsigned cvt_pk_bf16(float lo, float hi) {
    unsigned r;
    asm("v_cvt_pk_bf16_f32 %0, %1, %2" : "=v"(r) : "v"(lo), "v"(hi));
    return r;
}
__device__ __forceinline__ void gl_lds16(const ushort* g, ushort* l) {
    __builtin_amdgcn_global_load_lds(
        (const __attribute__((address_space(1))) void*)g,
        (__attribute__((address_space(3))) void*)l, 16, 0, 0);
}

// ---------------------------------------------------------------------------
// Batched fp32 -> bf16 cast. grid (4096, 1, nz), block 256: 4 el/thread.
// ---------------------------------------------------------------------------
struct CB { const float* src[2]; ushort* dst[2]; };

__global__ __launch_bounds__(256) void castb(CB cb) {
    const int z = blockIdx.z;
    const float* s = cb.src[z];
    ushort* d = cb.dst[z];
    const size_t i = ((size_t)blockIdx.x * 256 + threadIdx.x) * 4;
    floatx4 f = *(const floatx4*)&s[i];
    short4v o;
#pragma unroll
    for (int k = 0; k < 4; k++) o[k] = (short)f2bf(f[k]);
    *(short4v*)&d[i] = o;
}

// ---------------------------------------------------------------------------
// Batched fp32->bf16 weight transpose: Wt[n*K+k] = bf16(W[k*N+n])
// ---------------------------------------------------------------------------
struct TB { const float* src[4]; ushort* dst[4]; int K[4]; int N[4]; };

__global__ __launch_bounds__(256) void tbatch(TB tb) {
    __shared__ float tile[32][33];
    const int wi = blockIdx.z;
    const int K = tb.K[wi], N = tb.N[wi];
    const int k0 = blockIdx.x * 32, n0 = blockIdx.y * 32;
    if (k0 >= K || n0 >= N) return;
    const float* W = tb.src[wi];
    ushort* Wt = tb.dst[wi];
    const int tx = threadIdx.x & 31, ty = threadIdx.x >> 5;
#pragma unroll
    for (int i = ty; i < 32; i += 8)
        tile[i][tx] = W[(size_t)(k0 + i) * N + n0 + tx];
    __syncthreads();
#pragma unroll
    for (int i = ty; i < 32; i += 8)
        Wt[(size_t)(n0 + i) * K + k0 + tx] = f2bf(tile[tx][i]);
}

// ---------------------------------------------------------------------------
// Q-GEMM, 128x64 tile, BK=64 (R8 proven): C = cscale*(A[4096x1024] @ Bt^T),
// Bt [2048][1024], C bf16 ldc=2048. grid (32, 32) = 1024 blocks = 4/CU.
// Twin K=32 sub-tiles per barrier pair -> 16 MFMA / 2 barriers. LDS 24KB.
// ---------------------------------------------------------------------------
__global__ __launch_bounds__(256) void gemm_q(
    const ushort* __restrict__ A, const ushort* __restrict__ Bt,
    ushort* __restrict__ C, float cscale)
{
    __shared__ ushort As0[128 * 32];
    __shared__ ushort As1[128 * 32];
    __shared__ ushort Bs0[64 * 32];
    __shared__ ushort Bs1[64 * 32];
    const int t = threadIdx.x;
    const int lane = t & 63, w = t >> 6;
    const int q = lane >> 4, li = lane & 15;
    const int rowA = blockIdx.x * 128, colB = blockIdx.y * 64;
    const int ar = rowA + w * 32 + (lane >> 2);
    const int br = colB + w * 16 + (lane >> 2);
    const int cl = (lane & 3) * 8;
    ushort* adst0 = &As0[w * 32 * 32];
    ushort* adst1 = &As1[w * 32 * 32];
    ushort* bdst0 = &Bs0[w * 16 * 32];
    ushort* bdst1 = &Bs1[w * 16 * 32];

    floatx4 acc[2][4];
    const floatx4 z4 = {0.f, 0.f, 0.f, 0.f};
#pragma unroll
    for (int i = 0; i < 2; i++)
#pragma unroll
        for (int j = 0; j < 4; j++) acc[i][j] = z4;

    for (int k0 = 0; k0 < 1024; k0 += 64) {
        gl_lds16(A + (size_t)ar * 1024 + k0 + cl, adst0);
        gl_lds16(A + (size_t)(ar + 16) * 1024 + k0 + cl, adst0 + 16 * 32);
        gl_lds16(A + (size_t)ar * 1024 + k0 + 32 + cl, adst1);
        gl_lds16(A + (size_t)(ar + 16) * 1024 + k0 + 32 + cl, adst1 + 16 * 32);
        gl_lds16(Bt + (size_t)br * 1024 + k0 + cl, bdst0);
        gl_lds16(Bt + (size_t)br * 1024 + k0 + 32 + cl, bdst1);
        __syncthreads();
        short8 af[2], bf[4];
#pragma unroll
        for (int i = 0; i < 2; i++) af[i] = *(const short8*)&As0[(w * 32 + i * 16 + li) * 32 + q * 8];
#pragma unroll
        for (int j = 0; j < 4; j++) bf[j] = *(const short8*)&Bs0[(j * 16 + li) * 32 + q * 8];
#pragma unroll
        for (int i = 0; i < 2; i++)
#pragma unroll
            for (int j = 0; j < 4; j++)
                acc[i][j] = __builtin_amdgcn_mfma_f32_16x16x32_bf16(af[i], bf[j], acc[i][j], 0, 0, 0);
#pragma unroll
        for (int i = 0; i < 2; i++) af[i] = *(const short8*)&As1[(w * 32 + i * 16 + li) * 32 + q * 8];
#pragma unroll
        for (int j = 0; j < 4; j++) bf[j] = *(const short8*)&Bs1[(j * 16 + li) * 32 + q * 8];
#pragma unroll
        for (int i = 0; i < 2; i++)
#pragma unroll
            for (int j = 0; j < 4; j++)
                acc[i][j] = __builtin_amdgcn_mfma_f32_16x16x32_bf16(af[i], bf[j], acc[i][j], 0, 0, 0);
        __syncthreads();
    }
#pragma unroll
    for (int i = 0; i < 2; i++) {
        const int rowb = rowA + w * 32 + i * 16 + q * 4;
#pragma unroll
        for (int j = 0; j < 4; j++) {
            const int col = colB + j * 16 + li;
#pragma unroll
            for (int r = 0; r < 4; r++)
                C[(size_t)(rowb + r) * 2048 + col] = f2bf(acc[i][j][r] * cscale);
        }
    }
}

// ---------------------------------------------------------------------------
// KV-GEMM (z=2 batched): C = A[4096x1024] @ Bt[128][1024]^T; epilogue splits
// cols 0-63 -> Kp[row*64+col], 64-127 -> Vt[b][d][tok]. grid (32,1,2).
// ---------------------------------------------------------------------------
__global__ __launch_bounds__(256) void gemm_kv(
    const ushort* __restrict__ A0, const ushort* __restrict__ A1,
    const ushort* __restrict__ B0, const ushort* __restrict__ B1,
    ushort* __restrict__ C0, ushort* __restrict__ C1,
    ushort* __restrict__ vt0, ushort* __restrict__ vt1)
{
    __shared__ ushort As[128 * 32];
    __shared__ ushort Bs[128 * 32];
    const int z = blockIdx.z;
    const ushort* A = z ? A1 : A0;
    const ushort* Bt = z ? B1 : B0;
    ushort* Kp = z ? C1 : C0;
    ushort* vt = z ? vt1 : vt0;

    const int t = threadIdx.x;
    const int lane = t & 63, w = t >> 6;
    const int q = lane >> 4, li = lane & 15;
    const int wr = (w >> 1) * 64, wc = (w & 1) * 64;
    const int rowA = blockIdx.x * 128;
    const int ar = rowA + w * 32 + (lane >> 2);
    const int br = w * 32 + (lane >> 2);
    const int cl = (lane & 3) * 8;
    ushort* adst = &As[w * 32 * 32];
    ushort* bdst = &Bs[w * 32 * 32];

    floatx4 acc[4][4];
    const floatx4 z4 = {0.f, 0.f, 0.f, 0.f};
#pragma unroll
    for (int i = 0; i < 4; i++)
#pragma unroll
        for (int j = 0; j < 4; j++) acc[i][j] = z4;

    for (int k0 = 0; k0 < 1024; k0 += 32) {
        gl_lds16(A + (size_t)ar * 1024 + k0 + cl, adst);
        gl_lds16(A + (size_t)(ar + 16) * 1024 + k0 + cl, adst + 16 * 32);
        gl_lds16(Bt + (size_t)br * 1024 + k0 + cl, bdst);
        gl_lds16(Bt + (size_t)(br + 16) * 1024 + k0 + cl, bdst + 16 * 32);
        __syncthreads();
        short8 af[4], bf[4];
#pragma unroll
        for (int i = 0; i < 4; i++) af[i] = *(const short8*)&As[(wr + i * 16 + li) * 32 + q * 8];
#pragma unroll
        for (int j = 0; j < 4; j++) bf[j] = *(const short8*)&Bs[(wc + j * 16 + li) * 32 + q * 8];
#pragma unroll
        for (int i = 0; i < 4; i++)
#pragma unroll
            for (int j = 0; j < 4; j++)
                acc[i][j] = __builtin_amdgcn_mfma_f32_16x16x32_bf16(af[i], bf[j], acc[i][j], 0, 0, 0);
        __syncthreads();
    }
#pragma unroll
    for (int i = 0; i < 4; i++) {
        const int rowb = rowA + wr + i * 16 + q * 4;
#pragma unroll
        for (int j = 0; j < 4; j++) {
            const int col = wc + j * 16 + li;
#pragma unroll
            for (int r = 0; r < 4; r++) {
                const int row = rowb + r;
                const ushort vb = f2bf(acc[i][j][r]);
                if (col < 64) Kp[(size_t)row * 64 + col] = vb;
                else vt[((row >> 10) << 16) + ((col - 64) << 10) + (row & 1023)] = vb;
            }
        }
    }
}

// ---------------------------------------------------------------------------
// Fused concat-projection GEMM, 128x64 tile, BK=64 (R8 proven), K=2048:
// C = [A1|A2] @ Bt^T + bias (fp32 out). grid (32, 16) = 512 blocks = 2/CU.
// ---------------------------------------------------------------------------
__global__ __launch_bounds__(256) void gemm_proj(
    const ushort* __restrict__ A1, const ushort* __restrict__ A2,
    const ushort* __restrict__ Bt, const float* __restrict__ bias,
    float* __restrict__ C)
{
    __shared__ ushort As0[128 * 32];
    __shared__ ushort As1[128 * 32];
    __shared__ ushort Bs0[64 * 32];
    __shared__ ushort Bs1[64 * 32];
    const int t = threadIdx.x;
    const int lane = t & 63, w = t >> 6;
    const int q = lane >> 4, li = lane & 15;
    const int rowA = blockIdx.x * 128, colB = blockIdx.y * 64;
    const int ar = rowA + w * 32 + (lane >> 2);
    const int br = colB + w * 16 + (lane >> 2);
    const int cl = (lane & 3) * 8;
    ushort* adst0 = &As0[w * 32 * 32];
    ushort* adst1 = &As1[w * 32 * 32];
    ushort* bdst0 = &Bs0[w * 16 * 32];
    ushort* bdst1 = &Bs1[w * 16 * 32];

    floatx4 acc[2][4];
    const floatx4 z4 = {0.f, 0.f, 0.f, 0.f};
#pragma unroll
    for (int i = 0; i < 2; i++)
#pragma unroll
        for (int j = 0; j < 4; j++) acc[i][j] = z4;

    for (int k0 = 0; k0 < 2048; k0 += 64) {
        const ushort* Ap = (k0 < 1024) ? A1 : A2;
        const int kc = k0 & 1023;
        const int kp0 = kc + cl;
        const int kp1 = kc + 32 + cl;
        const int koff = (k0 >= 1024) ? 64 : 0;
        const int ks0 = ((kp0 >> 6) << 7) + (kp0 & 63) + koff;
        const int ks1 = ((kp1 >> 6) << 7) + (kp1 & 63) + koff;
        gl_lds16(Ap + (size_t)ar * 1024 + kc + cl, adst0);
        gl_lds16(Ap + (size_t)(ar + 16) * 1024 + kc + cl, adst0 + 16 * 32);
        gl_lds16(Ap + (size_t)ar * 1024 + kc + 32 + cl, adst1);
        gl_lds16(Ap + (size_t)(ar + 16) * 1024 + kc + 32 + cl, adst1 + 16 * 32);
        gl_lds16(Bt + (size_t)br * 2048 + ks0, bdst0);
        gl_lds16(Bt + (size_t)br * 2048 + ks1, bdst1);
        __syncthreads();
        short8 af[2], bf[4];
#pragma unroll
        for (int i = 0; i < 2; i++) af[i] = *(const short8*)&As0[(w * 32 + i * 16 + li) * 32 + q * 8];
#pragma unroll
        for (int j = 0; j < 4; j++) bf[j] = *(const short8*)&Bs0[(j * 16 + li) * 32 + q * 8];
#pragma unroll
        for (int i = 0; i < 2; i++)
#pragma unroll
            for (int j = 0; j < 4; j++)
                acc[i][j] = __builtin_amdgcn_mfma_f32_16x16x32_bf16(af[i], bf[j], acc[i][j], 0, 0, 0);
#pragma unroll
        for (int i = 0; i < 2; i++) af[i] = *(const short8*)&As1[(w * 32 + i * 16 + li) * 32 + q * 8];
#pragma unroll
        for (int j = 0; j < 4; j++) bf[j] = *(const short8*)&Bs1[(j * 16 + li) * 32 + q * 8];
#pragma unroll
        for (int i = 0; i < 2; i++)
#pragma unroll
            for (int j = 0; j < 4; j++)
                acc[i][j] = __builtin_amdgcn_mfma_f32_16x16x32_bf16(af[i], bf[j], acc[i][j], 0, 0, 0);
        __syncthreads();
    }
#pragma unroll
    for (int i = 0; i < 2; i++) {
        const int rowb = rowA + w * 32 + i * 16 + q * 4;
#pragma unroll
        for (int j = 0; j < 4; j++) {
            const int col = colB + j * 16 + li;
            const float bv = bias[col];
#pragma unroll
            for (int r = 0; r < 4; r++)
                C[(size_t)(rowb + r) * 1024 + col] = acc[i][j][r] + bv;
        }
    }
}

// ---------------------------------------------------------------------------
// Flash attention v7: 32x32 swapped-QK^T in-reg softmax + DOUBLE-BUFFERED
// K/V LDS, single barrier per kt-iter (was 2). Per iter:
//   barrier; [write regs(kt+1)->buf[cur^1] || compute buf[cur]]; loads kt+2.
// Writers/readers of each buffer separated by exactly one barrier both ways.
// LDS 35.3KB -> 4 blk/CU (= grid cap, no occupancy loss). grid (8,16,8).
// ---------------------------------------------------------------------------
__global__ __launch_bounds__(256, 4) void attn_kernel(
    const ushort* __restrict__ Qbase,
    const ushort* __restrict__ KVa, const ushort* __restrict__ KVb,
    ushort* __restrict__ OutA, ushort* __restrict__ OutB)
{
    __shared__ ushort Kt[2][64 * 68];   // [buf][key][d]
    __shared__ ushort Vt[2][64 * 68];   // [buf][d][key]
    __shared__ __align__(16) float Ls[4][32];  // per-wave lsum transpose

    const int t = threadIdx.x;
    const int lane = t & 63, w = t >> 6;
    const int ql = lane & 31, hi = lane >> 5;
    const int qt = blockIdx.x, h = blockIdx.y;
    const int z = blockIdx.z, b = z >> 1, a2 = z & 1;

    const ushort* Q  = Qbase + (a2 ? 1024 : 0);
    const ushort* KV = a2 ? KVb : KVa;
    ushort* Out      = a2 ? OutB : OutA;
    const ushort* Kp = KV;
    const ushort* Vg = KV + 262144;

    const size_t qrow = (size_t)(b * 1024 + qt * 128 + w * 32 + ql);
    short8 qf[4];
#pragma unroll
    for (int dc = 0; dc < 4; dc++)
        qf[dc] = *(const short8*)&Q[qrow * 2048 + h * 64 + dc * 16 + hi * 8];

    float lsum = 0.f;
    floatx16 accO[2];
#pragma unroll
    for (int dt = 0; dt < 2; dt++)
#pragma unroll
        for (int i = 0; i < 16; i++) accO[dt][i] = 0.f;

    const int srow = t >> 2, sch = (t & 3) * 16;
    const ushort* ksrc0 = &Kp[(size_t)(b * 1024 + srow) * 64 + sch];
    const ushort* vsrc0 = &Vg[(size_t)(b * 64 + srow) * 1024 + sch];
    const int soff = srow * 68 + sch;

    short8 kreg[2], vreg[2];
    // prologue: tile 0 -> regs -> buf0; tile 1 -> regs
#pragma unroll
    for (int i = 0; i < 2; i++) {
        kreg[i] = *(const short8*)&ksrc0[i * 8];
        vreg[i] = *(const short8*)&vsrc0[i * 8];
    }
#pragma unroll
    for (int i = 0; i < 2; i++) {
        *(short8*)&Kt[0][soff + i * 8] = kreg[i];
        *(short8*)&Vt[0][soff + i * 8] = vreg[i];
    }
#pragma unroll
    for (int i = 0; i < 2; i++) {
        kreg[i] = *(const short8*)&ksrc0[64 * 64 + i * 8];
        vreg[i] = *(const short8*)&vsrc0[64 + i * 8];
    }

    for (int kt = 0; kt < 16; kt++) {
        const int cur = kt & 1;
        __syncthreads();   // buf[cur] writes visible; buf[cur^1] readers done

        // write next tile (kt+1) into buf[cur^1]; overlaps with compute below
        if (kt < 15) {
#pragma unroll
            for (int i = 0; i < 2; i++) {
                *(short8*)&Kt[cur ^ 1][soff + i * 8] = kreg[i];
                *(short8*)&Vt[cur ^ 1][soff + i * 8] = vreg[i];
            }
        }
        // issue loads for kt+2; drain at next top-barrier (full iter of cover)
        if (kt < 14) {
            const ushort* ksrc = ksrc0 + (size_t)(kt + 2) * 64 * 64;
            const ushort* vsrc = vsrc0 + (kt + 2) * 64;
#pragma unroll
            for (int i = 0; i < 2; i++) {
                kreg[i] = *(const short8*)&ksrc[i * 8];
                vreg[i] = *(const short8*)&vsrc[i * 8];
            }
        }

#pragma unroll
        for (int ktile = 0; ktile < 2; ktile++) {
            floatx16 S;
#pragma unroll
            for (int i = 0; i < 16; i++) S[i] = 0.f;
            __builtin_amdgcn_s_setprio(1);
#pragma unroll
            for (int dc = 0; dc < 4; dc++) {
                short8 kf = *(const short8*)&Kt[cur][(ktile * 32 + ql) * 68 + dc * 16 + hi * 8];
                S = __builtin_amdgcn_mfma_f32_32x32x16_bf16(kf, qf[dc], S, 0, 0, 0);
            }
            __builtin_amdgcn_s_setprio(0);

            float e[16];
#pragma unroll
            for (int r = 0; r < 16; r++) e[r] = __expf(S[r]);
            float sa = (e[0] + e[1]) + (e[2] + e[3]);
            float sb = (e[4] + e[5]) + (e[6] + e[7]);
            float sc = (e[8] + e[9]) + (e[10] + e[11]);
            float sd = (e[12] + e[13]) + (e[14] + e[15]);
            lsum += (sa + sb) + (sc + sd);

#pragma unroll
            for (int p = 0; p < 2; p++) {
                unsigned cA = cvt_pk_bf16(e[8 * p + 0], e[8 * p + 1]);
                unsigned cC = cvt_pk_bf16(e[8 * p + 2], e[8 * p + 3]);
                unsigned cB = cvt_pk_bf16(e[8 * p + 4], e[8 * p + 5]);
                unsigned cD = cvt_pk_bf16(e[8 * p + 6], e[8 * p + 7]);
                uintx2 s02 = __builtin_amdgcn_permlane32_swap(cA, cB, false, false);
                uintx2 s13 = __builtin_amdgcn_permlane32_swap(cC, cD, false, false);
                union { unsigned u[4]; short8 s; } pf;
                pf.u[0] = s02[0]; pf.u[1] = s13[0];
                pf.u[2] = s02[1]; pf.u[3] = s13[1];
                const int kslot = ktile * 2 + p;
                __builtin_amdgcn_s_setprio(1);
#pragma unroll
                for (int dt = 0; dt < 2; dt++) {
                    short8 vf = *(const short8*)&Vt[cur][(dt * 32 + ql) * 68 + kslot * 16 + hi * 8];
                    accO[dt] = __builtin_amdgcn_mfma_f32_32x32x16_bf16(pf.s, vf, accO[dt], 0, 0, 0);
                }
                __builtin_amdgcn_s_setprio(0);
            }
        }
        // no end-of-iter barrier: next top-barrier separates buffer roles
    }

    lsum += __shfl_xor(lsum, 32);
    Ls[w][ql] = lsum;

    const int orow0 = b * 1024 + qt * 128 + w * 32;
#pragma unroll
    for (int g = 0; g < 4; g++) {
        floatx4 L4 = *(const floatx4*)&Ls[w][g * 8 + hi * 4];
#pragma unroll
        for (int rr = 0; rr < 4; rr++) {
            const float inv = 1.f / L4[rr];
            const int row = orow0 + g * 8 + hi * 4 + rr;
#pragma unroll
            for (int dt = 0; dt < 2; dt++)
                Out[(size_t)row * 1024 + h * 64 + dt * 32 + ql] =
                    f2bf(accO[dt][g * 4 + rr] * inv);
        }
    }
}

// ---------------------------------------------------------------------------
extern "C" void kernel_launch(void* const* d_in, const int* in_sizes, int n_in,
                              void* d_out, int out_size, void* d_ws, size_t ws_size,
                              hipStream_t stream) {
    const float* qx    = (const float*)d_in[0];
    const float* kvx   = (const float*)d_in[1];
    const float* qs    = (const float*)d_in[2];
    const float* kvs   = (const float*)d_in[3];
    const float* w_qx1 = (const float*)d_in[4];
    const float* w_qs1 = (const float*)d_in[5];
    const float* w_qx2 = (const float*)d_in[6];
    const float* w_qs2 = (const float*)d_in[7];
    const float* w_kvx = (const float*)d_in[8];
    const float* w_kvs = (const float*)d_in[9];
    const float* w_xp  = (const float*)d_in[10];
    const float* b_xp  = (const float*)d_in[11];
    const float* w_sp  = (const float*)d_in[12];
    const float* b_sp  = (const float*)d_in[13];
    float* out = (float*)d_out;
    (void)ws_size; (void)in_sizes; (void)n_in; (void)out_size;

    ushort* ws   = (ushort*)d_ws;
    ushort* Wb   = ws;
    ushort* q1q2 = ws + 4194304;
    ushort* Mbuf = ws + 12582912;
    ushort* kvpx = ws + 16777216;
    ushort* kvps = ws + 17301504;

    // 1) cast kv activations: kvx_b -> Mbuf, kvs_b -> q1q2 (both dead regions)
    CB c1; c1.src[0] = kvx; c1.dst[0] = Mbuf; c1.src[1] = kvs; c1.dst[1] = q1q2;
    castb<<<dim3(4096, 1, 2), 256, 0, stream>>>(c1);

    // 2) transpose kv + s-path Q weights into Wb
    TB tb1;
    tb1.src[0] = w_kvx; tb1.dst[0] = Wb;           tb1.K[0] = 1024; tb1.N[0] = 128;
    tb1.src[1] = w_kvs; tb1.dst[1] = Wb + 131072;  tb1.K[1] = 1024; tb1.N[1] = 128;
    tb1.src[2] = w_qs1; tb1.dst[2] = Wb + 262144;  tb1.K[2] = 1024; tb1.N[2] = 1024;
    tb1.src[3] = w_qs2; tb1.dst[3] = Wb + 1310720; tb1.K[3] = 1024; tb1.N[3] = 1024;
    tbatch<<<dim3(32, 32, 4), 256, 0, stream>>>(tb1);

    // 3) kv projections (z=2): K->Kp, V->Vt
    gemm_kv<<<dim3(32, 1, 2), 256, 0, stream>>>(
        Mbuf, q1q2, Wb, Wb + 131072, kvpx, kvps, kvpx + 262144, kvps + 262144);

    // 4) cast qs -> Mbuf (kvx_b dead)
    CB c2; c2.src[0] = qs; c2.dst[0] = Mbuf; c2.src[1] = qs; c2.dst[1] = Mbuf;
    castb<<<dim3(4096, 1, 1), 256, 0, stream>>>(c2);

    // 5) s-path Q GEMM: q1s|q2s -> q1q2 (kvs_b dead), scale 1/8 folded
    gemm_q<<<dim3(32, 32), 256, 0, stream>>>(Mbuf, Wb + 262144, q1q2, 0.125f);

    // 6) s attention: M_s -> Mbuf (qs_b dead), M_sx -> d_out lo (bf16 scratch)
    attn_kernel<<<dim3(8, 16, 8), 256, 0, stream>>>(q1q2, kvps, kvpx, Mbuf, (ushort*)out);

    // 7) transpose sp + x-path Q weights (Wt_kv/Wt_qs dead)
    TB tb2;
    tb2.src[0] = w_sp;  tb2.dst[0] = Wb;           tb2.K[0] = 2048; tb2.N[0] = 1024;
    tb2.src[1] = w_qx1; tb2.dst[1] = Wb + 2097152; tb2.K[1] = 1024; tb2.N[1] = 1024;
    tb2.src[2] = w_qx2; tb2.dst[2] = Wb + 3145728; tb2.K[2] = 1024; tb2.N[2] = 1024;
    tb2.src[3] = w_sp;  tb2.dst[3] = Wb;           tb2.K[3] = 0;    tb2.N[3] = 0;
    tbatch<<<dim3(64, 32, 3), 256, 0, stream>>>(tb2);

    // 8) s_out = [M_sx | M_s] @ Wsp^T + b_sp -> d_out hi (fp32)
    gemm_proj<<<dim3(32, 16), 256, 0, stream>>>((ushort*)out, Mbuf, Wb, b_sp, out + 4194304);

    // 9) cast qx -> Mbuf (M_s dead)
    CB c3; c3.src[0] = qx; c3.dst[0] = Mbuf; c3.src[1] = qx; c3.dst[1] = Mbuf;
    castb<<<dim3(4096, 1, 1), 256, 0, stream>>>(c3);

    // 10) x-path Q GEMM -> q1q2 (dead after s-attn)
    gemm_q<<<dim3(32, 32), 256, 0, stream>>>(Mbuf, Wb + 2097152, q1q2, 0.125f);

    // 11) x attention: M_x -> Mbuf (qx_b dead), M_xs -> Wb (weights dead)
    attn_kernel<<<dim3(8, 16, 8), 256, 0, stream>>>(q1q2, kvpx, kvps, Mbuf, Wb);

    // 12) transpose xp -> q1q2 (dead after x-attn)
    TB tb3;
    tb3.src[0] = w_xp; tb3.dst[0] = q1q2; tb3.K[0] = 2048; tb3.N[0] = 1024;
    tb3.src[1] = w_xp; tb3.dst[1] = q1q2; tb3.K[1] = 0;    tb3.N[1] = 0;
    tb3.src[2] = w_xp; tb3.dst[2] = q1q2; tb3.K[2] = 0;    tb3.N[2] = 0;
    tb3.src[3] = w_xp; tb3.dst[3] = q1q2; tb3.K[3] = 0;    tb3.N[3] = 0;
    tbatch<<<dim3(64, 32, 1), 256, 0, stream>>>(tb3);

    // 13) x_out = [M_xs | M_x] @ Wxp^T + b_xp -> d_out lo (M_sx scratch dead)
    gemm_proj<<<dim3(32, 16), 256, 0, stream>>>(Wb, Mbuf, q1q2, b_xp, out);
}

// Round 12
// 413.676 us; speedup vs baseline: 1.0552x; 1.0167x over previous
//
#include <hip/hip_runtime.h>
#include <hip/hip_bf16.h>

// ---------------------------------------------------------------------------
// RecurrentAttention: B=4, L=1024, D_MODEL=1024, N_HEAD=16, D_HEAD=64
// Inputs/outputs fp32; internals bf16, fp32 accumulate.
//
// ws (bf16-el units, 35.65 MB proven-safe):
//   Wb    [0, 4194304)         weights rotate -> M_xs (x-attn OutB)
//   q1q2  [4194304, 12582912)  kvs_b -> Q outputs [4096x2048] -> Wt_xp
//   Mbuf  [12582912, 16777216) kvx_b -> qs_b -> M_s -> qx_b -> M_x
//   kvpx  [16777216,+524288)   Kp [4096x64] + Vt [4][64][1024]
//   kvps  [17301504,+524288)
// d_out lo = bf16 scratch for M_sx (dead before final x_out write).
// All launches sequential on one stream -> aliasing race-free.
//
// v12 (R11 post-mortem): v7-attn's conditional prefetch (`if kt<15/14`)
// caused SCRATCH SPILLS — FETCH/WRITE_SIZE +43MB/dispatch (~90B/thread),
// eating the single-barrier gain and polluting L2. v8-attn: BRANCH-FREE
// pipeline — unconditional stage-write of tile kt+1 (kt=15 rewrites dead
// buffer, harmless) + unconditional clamped prefetch of tile min(kt+2,15)
// (valid address, values unused). GEMMs = R8-proven (128x64 BK=64 twin).
// ---------------------------------------------------------------------------

typedef short short8 __attribute__((ext_vector_type(8)));
typedef short short4v __attribute__((ext_vector_type(4)));
typedef float floatx4 __attribute__((ext_vector_type(4)));
typedef float floatx16 __attribute__((ext_vector_type(16)));
typedef unsigned uintx2 __attribute__((ext_vector_type(2)));

__device__ __forceinline__ float b2f(ushort h) {
    union { unsigned u; float f; } v; v.u = ((unsigned)h) << 16; return v.f;
}
__device__ __forceinline__ ushort f2bf(float f) {
    union { float f; unsigned u; } v; v.f = f;
    return (ushort)((v.u + 0x7FFFu + ((v.u >> 16) & 1u)) >> 16);
}
__device__ __forceinline__ unsigned cvt_pk_bf16(float lo, float hi) {
    unsigned r;
    asm("v_cvt_pk_bf16_f32 %0, %1, %2" : "=v"(r) : "v"(lo), "v"(hi));
    return r;
}
__device__ __forceinline__ void gl_lds16(const ushort* g, ushort* l) {
    __builtin_amdgcn_global_load_lds(
        (const __attribute__((address_space(1))) void*)g,
        (__attribute__((address_space(3))) void*)l, 16, 0, 0);
}

// ---------------------------------------------------------------------------
// Batched fp32 -> bf16 cast. grid (4096, 1, nz), block 256: 4 el/thread.
// ---------------------------------------------------------------------------
struct CB { const float* src[2]; ushort* dst[2]; };

__global__ __launch_bounds__(256) void castb(CB cb) {
    const int z = blockIdx.z;
    const float* s = cb.src[z];
    ushort* d = cb.dst[z];
    const size_t i = ((size_t)blockIdx.x * 256 + threadIdx.x) * 4;
    floatx4 f = *(const floatx4*)&s[i];
    short4v o;
#pragma unroll
    for (int k = 0; k < 4; k++) o[k] = (short)f2bf(f[k]);
    *(short4v*)&d[i] = o;
}

// ---------------------------------------------------------------------------
// Batched fp32->bf16 weight transpose: Wt[n*K+k] = bf16(W[k*N+n])
// ---------------------------------------------------------------------------
struct TB { const float* src[4]; ushort* dst[4]; int K[4]; int N[4]; };

__global__ __launch_bounds__(256) void tbatch(TB tb) {
    __shared__ float tile[32][33];
    const int wi = blockIdx.z;
    const int K = tb.K[wi], N = tb.N[wi];
    const int k0 = blockIdx.x * 32, n0 = blockIdx.y * 32;
    if (k0 >= K || n0 >= N) return;
    const float* W = tb.src[wi];
    ushort* Wt = tb.dst[wi];
    const int tx = threadIdx.x & 31, ty = threadIdx.x >> 5;
#pragma unroll
    for (int i = ty; i < 32; i += 8)
        tile[i][tx] = W[(size_t)(k0 + i) * N + n0 + tx];
    __syncthreads();
#pragma unroll
    for (int i = ty; i < 32; i += 8)
        Wt[(size_t)(n0 + i) * K + k0 + tx] = f2bf(tile[tx][i]);
}

// ---------------------------------------------------------------------------
// Q-GEMM, 128x64 tile, BK=64 (R8 proven): C = cscale*(A[4096x1024] @ Bt^T),
// Bt [2048][1024], C bf16 ldc=2048. grid (32, 32) = 1024 blocks = 4/CU.
// Twin K=32 sub-tiles per barrier pair -> 16 MFMA / 2 barriers. LDS 24KB.
// ---------------------------------------------------------------------------
__global__ __launch_bounds__(256) void gemm_q(
    const ushort* __restrict__ A, const ushort* __restrict__ Bt,
    ushort* __restrict__ C, float cscale)
{
    __shared__ ushort As0[128 * 32];
    __shared__ ushort As1[128 * 32];
    __shared__ ushort Bs0[64 * 32];
    __shared__ ushort Bs1[64 * 32];
    const int t = threadIdx.x;
    const int lane = t & 63, w = t >> 6;
    const int q = lane >> 4, li = lane & 15;
    const int rowA = blockIdx.x * 128, colB = blockIdx.y * 64;
    const int ar = rowA + w * 32 + (lane >> 2);
    const int br = colB + w * 16 + (lane >> 2);
    const int cl = (lane & 3) * 8;
    ushort* adst0 = &As0[w * 32 * 32];
    ushort* adst1 = &As1[w * 32 * 32];
    ushort* bdst0 = &Bs0[w * 16 * 32];
    ushort* bdst1 = &Bs1[w * 16 * 32];

    floatx4 acc[2][4];
    const floatx4 z4 = {0.f, 0.f, 0.f, 0.f};
#pragma unroll
    for (int i = 0; i < 2; i++)
#pragma unroll
        for (int j = 0; j < 4; j++) acc[i][j] = z4;

    for (int k0 = 0; k0 < 1024; k0 += 64) {
        gl_lds16(A + (size_t)ar * 1024 + k0 + cl, adst0);
        gl_lds16(A + (size_t)(ar + 16) * 1024 + k0 + cl, adst0 + 16 * 32);
        gl_lds16(A + (size_t)ar * 1024 + k0 + 32 + cl, adst1);
        gl_lds16(A + (size_t)(ar + 16) * 1024 + k0 + 32 + cl, adst1 + 16 * 32);
        gl_lds16(Bt + (size_t)br * 1024 + k0 + cl, bdst0);
        gl_lds16(Bt + (size_t)br * 1024 + k0 + 32 + cl, bdst1);
        __syncthreads();
        short8 af[2], bf[4];
#pragma unroll
        for (int i = 0; i < 2; i++) af[i] = *(const short8*)&As0[(w * 32 + i * 16 + li) * 32 + q * 8];
#pragma unroll
        for (int j = 0; j < 4; j++) bf[j] = *(const short8*)&Bs0[(j * 16 + li) * 32 + q * 8];
#pragma unroll
        for (int i = 0; i < 2; i++)
#pragma unroll
            for (int j = 0; j < 4; j++)
                acc[i][j] = __builtin_amdgcn_mfma_f32_16x16x32_bf16(af[i], bf[j], acc[i][j], 0, 0, 0);
#pragma unroll
        for (int i = 0; i < 2; i++) af[i] = *(const short8*)&As1[(w * 32 + i * 16 + li) * 32 + q * 8];
#pragma unroll
        for (int j = 0; j < 4; j++) bf[j] = *(const short8*)&Bs1[(j * 16 + li) * 32 + q * 8];
#pragma unroll
        for (int i = 0; i < 2; i++)
#pragma unroll
            for (int j = 0; j < 4; j++)
                acc[i][j] = __builtin_amdgcn_mfma_f32_16x16x32_bf16(af[i], bf[j], acc[i][j], 0, 0, 0);
        __syncthreads();
    }
#pragma unroll
    for (int i = 0; i < 2; i++) {
        const int rowb = rowA + w * 32 + i * 16 + q * 4;
#pragma unroll
        for (int j = 0; j < 4; j++) {
            const int col = colB + j * 16 + li;
#pragma unroll
            for (int r = 0; r < 4; r++)
                C[(size_t)(rowb + r) * 2048 + col] = f2bf(acc[i][j][r] * cscale);
        }
    }
}

// ---------------------------------------------------------------------------
// KV-GEMM (z=2 batched): C = A[4096x1024] @ Bt[128][1024]^T; epilogue splits
// cols 0-63 -> Kp[row*64+col], 64-127 -> Vt[b][d][tok]. grid (32,1,2).
// ---------------------------------------------------------------------------
__global__ __launch_bounds__(256) void gemm_kv(
    const ushort* __restrict__ A0, const ushort* __restrict__ A1,
    const ushort* __restrict__ B0, const ushort* __restrict__ B1,
    ushort* __restrict__ C0, ushort* __restrict__ C1,
    ushort* __restrict__ vt0, ushort* __restrict__ vt1)
{
    __shared__ ushort As[128 * 32];
    __shared__ ushort Bs[128 * 32];
    const int z = blockIdx.z;
    const ushort* A = z ? A1 : A0;
    const ushort* Bt = z ? B1 : B0;
    ushort* Kp = z ? C1 : C0;
    ushort* vt = z ? vt1 : vt0;

    const int t = threadIdx.x;
    const int lane = t & 63, w = t >> 6;
    const int q = lane >> 4, li = lane & 15;
    const int wr = (w >> 1) * 64, wc = (w & 1) * 64;
    const int rowA = blockIdx.x * 128;
    const int ar = rowA + w * 32 + (lane >> 2);
    const int br = w * 32 + (lane >> 2);
    const int cl = (lane & 3) * 8;
    ushort* adst = &As[w * 32 * 32];
    ushort* bdst = &Bs[w * 32 * 32];

    floatx4 acc[4][4];
    const floatx4 z4 = {0.f, 0.f, 0.f, 0.f};
#pragma unroll
    for (int i = 0; i < 4; i++)
#pragma unroll
        for (int j = 0; j < 4; j++) acc[i][j] = z4;

    for (int k0 = 0; k0 < 1024; k0 += 32) {
        gl_lds16(A + (size_t)ar * 1024 + k0 + cl, adst);
        gl_lds16(A + (size_t)(ar + 16) * 1024 + k0 + cl, adst + 16 * 32);
        gl_lds16(Bt + (size_t)br * 1024 + k0 + cl, bdst);
        gl_lds16(Bt + (size_t)(br + 16) * 1024 + k0 + cl, bdst + 16 * 32);
        __syncthreads();
        short8 af[4], bf[4];
#pragma unroll
        for (int i = 0; i < 4; i++) af[i] = *(const short8*)&As[(wr + i * 16 + li) * 32 + q * 8];
#pragma unroll
        for (int j = 0; j < 4; j++) bf[j] = *(const short8*)&Bs[(wc + j * 16 + li) * 32 + q * 8];
#pragma unroll
        for (int i = 0; i < 4; i++)
#pragma unroll
            for (int j = 0; j < 4; j++)
                acc[i][j] = __builtin_amdgcn_mfma_f32_16x16x32_bf16(af[i], bf[j], acc[i][j], 0, 0, 0);
        __syncthreads();
    }
#pragma unroll
    for (int i = 0; i < 4; i++) {
        const int rowb = rowA + wr + i * 16 + q * 4;
#pragma unroll
        for (int j = 0; j < 4; j++) {
            const int col = wc + j * 16 + li;
#pragma unroll
            for (int r = 0; r < 4; r++) {
                const int row = rowb + r;
                const ushort vb = f2bf(acc[i][j][r]);
                if (col < 64) Kp[(size_t)row * 64 + col] = vb;
                else vt[((row >> 10) << 16) + ((col - 64) << 10) + (row & 1023)] = vb;
            }
        }
    }
}

// ---------------------------------------------------------------------------
// Fused concat-projection GEMM, 128x64 tile, BK=64 (R8 proven), K=2048:
// C = [A1|A2] @ Bt^T + bias (fp32 out). grid (32, 16) = 512 blocks = 2/CU.
// ---------------------------------------------------------------------------
__global__ __launch_bounds__(256) void gemm_proj(
    const ushort* __restrict__ A1, const ushort* __restrict__ A2,
    const ushort* __restrict__ Bt, const float* __restrict__ bias,
    float* __restrict__ C)
{
    __shared__ ushort As0[128 * 32];
    __shared__ ushort As1[128 * 32];
    __shared__ ushort Bs0[64 * 32];
    __shared__ ushort Bs1[64 * 32];
    const int t = threadIdx.x;
    const int lane = t & 63, w = t >> 6;
    const int q = lane >> 4, li = lane & 15;
    const int rowA = blockIdx.x * 128, colB = blockIdx.y * 64;
    const int ar = rowA + w * 32 + (lane >> 2);
    const int br = colB + w * 16 + (lane >> 2);
    const int cl = (lane & 3) * 8;
    ushort* adst0 = &As0[w * 32 * 32];
    ushort* adst1 = &As1[w * 32 * 32];
    ushort* bdst0 = &Bs0[w * 16 * 32];
    ushort* bdst1 = &Bs1[w * 16 * 32];

    floatx4 acc[2][4];
    const floatx4 z4 = {0.f, 0.f, 0.f, 0.f};
#pragma unroll
    for (int i = 0; i < 2; i++)
#pragma unroll
        for (int j = 0; j < 4; j++) acc[i][j] = z4;

    for (int k0 = 0; k0 < 2048; k0 += 64) {
        const ushort* Ap = (k0 < 1024) ? A1 : A2;
        const int kc = k0 & 1023;
        const int kp0 = kc + cl;
        const int kp1 = kc + 32 + cl;
        const int koff = (k0 >= 1024) ? 64 : 0;
        const int ks0 = ((kp0 >> 6) << 7) + (kp0 & 63) + koff;
        const int ks1 = ((kp1 >> 6) << 7) + (kp1 & 63) + koff;
        gl_lds16(Ap + (size_t)ar * 1024 + kc + cl, adst0);
        gl_lds16(Ap + (size_t)(ar + 16) * 1024 + kc + cl, adst0 + 16 * 32);
        gl_lds16(Ap + (size_t)ar * 1024 + kc + 32 + cl, adst1);
        gl_lds16(Ap + (size_t)(ar + 16) * 1024 + kc + 32 + cl, adst1 + 16 * 32);
        gl_lds16(Bt + (size_t)br * 2048 + ks0, bdst0);
        gl_lds16(Bt + (size_t)br * 2048 + ks1, bdst1);
        __syncthreads();
        short8 af[2], bf[4];
#pragma unroll
        for (int i = 0; i < 2; i++) af[i] = *(const short8*)&As0[(w * 32 + i * 16 + li) * 32 + q * 8];
#pragma unroll
        for (int j = 0; j < 4; j++) bf[j] = *(const short8*)&Bs0[(j * 16 + li) * 32 + q * 8];
#pragma unroll
        for (int i = 0; i < 2; i++)
#pragma unroll
            for (int j = 0; j < 4; j++)
                acc[i][j] = __builtin_amdgcn_mfma_f32_16x16x32_bf16(af[i], bf[j], acc[i][j], 0, 0, 0);
#pragma unroll
        for (int i = 0; i < 2; i++) af[i] = *(const short8*)&As1[(w * 32 + i * 16 + li) * 32 + q * 8];
#pragma unroll
        for (int j = 0; j < 4; j++) bf[j] = *(const short8*)&Bs1[(j * 16 + li) * 32 + q * 8];
#pragma unroll
        for (int i = 0; i < 2; i++)
#pragma unroll
            for (int j = 0; j < 4; j++)
                acc[i][j] = __builtin_amdgcn_mfma_f32_16x16x32_bf16(af[i], bf[j], acc[i][j], 0, 0, 0);
        __syncthreads();
    }
#pragma unroll
    for (int i = 0; i < 2; i++) {
        const int rowb = rowA + w * 32 + i * 16 + q * 4;
#pragma unroll
        for (int j = 0; j < 4; j++) {
            const int col = colB + j * 16 + li;
            const float bv = bias[col];
#pragma unroll
            for (int r = 0; r < 4; r++)
                C[(size_t)(rowb + r) * 1024 + col] = acc[i][j][r] + bv;
        }
    }
}

// ---------------------------------------------------------------------------
// Flash attention v8: 32x32 swapped-QK^T in-reg softmax + double-buffered
// K/V LDS, single barrier per kt-iter, BRANCH-FREE pipeline (no spills):
//   barrier; write regs(kt+1)->buf[cur^1] (unconditional; kt=15 writes dead
//   buf); issue loads tile min(kt+2,15) (unconditional, clamped, values
//   unused on last iters); compute buf[cur].
// LDS 35.3KB -> 4 blk/CU (= grid cap). grid (8,16,8).
// ---------------------------------------------------------------------------
__global__ __launch_bounds__(256, 4) void attn_kernel(
    const ushort* __restrict__ Qbase,
    const ushort* __restrict__ KVa, const ushort* __restrict__ KVb,
    ushort* __restrict__ OutA, ushort* __restrict__ OutB)
{
    __shared__ ushort Kt[2][64 * 68];   // [buf][key][d]
    __shared__ ushort Vt[2][64 * 68];   // [buf][d][key]
    __shared__ __align__(16) float Ls[4][32];  // per-wave lsum transpose

    const int t = threadIdx.x;
    const int lane = t & 63, w = t >> 6;
    const int ql = lane & 31, hi = lane >> 5;
    const int qt = blockIdx.x, h = blockIdx.y;
    const int z = blockIdx.z, b = z >> 1, a2 = z & 1;

    const ushort* Q  = Qbase + (a2 ? 1024 : 0);
    const ushort* KV = a2 ? KVb : KVa;
    ushort* Out      = a2 ? OutB : OutA;
    const ushort* Kp = KV;
    const ushort* Vg = KV + 262144;

    const size_t qrow = (size_t)(b * 1024 + qt * 128 + w * 32 + ql);
    short8 qf[4];
#pragma unroll
    for (int dc = 0; dc < 4; dc++)
        qf[dc] = *(const short8*)&Q[qrow * 2048 + h * 64 + dc * 16 + hi * 8];

    float lsum = 0.f;
    floatx16 accO[2];
#pragma unroll
    for (int dt = 0; dt < 2; dt++)
#pragma unroll
        for (int i = 0; i < 16; i++) accO[dt][i] = 0.f;

    const int srow = t >> 2, sch = (t & 3) * 16;
    const ushort* ksrc0 = &Kp[(size_t)(b * 1024 + srow) * 64 + sch];
    const ushort* vsrc0 = &Vg[(size_t)(b * 64 + srow) * 1024 + sch];
    const int soff = srow * 68 + sch;

    short8 kreg[2], vreg[2];
    // prologue: tile 0 -> regs -> buf0; tile 1 -> regs
#pragma unroll
    for (int i = 0; i < 2; i++) {
        kreg[i] = *(const short8*)&ksrc0[i * 8];
        vreg[i] = *(const short8*)&vsrc0[i * 8];
    }
#pragma unroll
    for (int i = 0; i < 2; i++) {
        *(short8*)&Kt[0][soff + i * 8] = kreg[i];
        *(short8*)&Vt[0][soff + i * 8] = vreg[i];
    }
#pragma unroll
    for (int i = 0; i < 2; i++) {
        kreg[i] = *(const short8*)&ksrc0[64 * 64 + i * 8];
        vreg[i] = *(const short8*)&vsrc0[64 + i * 8];
    }

    for (int kt = 0; kt < 16; kt++) {
        const int cur = kt & 1;
        __syncthreads();   // buf[cur] writes visible; buf[cur^1] readers done

        // unconditional: write tile kt+1 into buf[cur^1]
        // (kt=15: rewrites tile-15 data into the dead buffer — never read)
#pragma unroll
        for (int i = 0; i < 2; i++) {
            *(short8*)&Kt[cur ^ 1][soff + i * 8] = kreg[i];
            *(short8*)&Vt[cur ^ 1][soff + i * 8] = vreg[i];
        }
        // unconditional clamped prefetch of tile min(kt+2,15); values of the
        // clamped iterations are never consumed (branch-free -> no spills)
        {
            const int nt = (kt + 2 > 15) ? 15 : (kt + 2);
            const ushort* ksrc = ksrc0 + (size_t)nt * 64 * 64;
            const ushort* vsrc = vsrc0 + nt * 64;
#pragma unroll
            for (int i = 0; i < 2; i++) {
                kreg[i] = *(const short8*)&ksrc[i * 8];
                vreg[i] = *(const short8*)&vsrc[i * 8];
            }
        }

#pragma unroll
        for (int ktile = 0; ktile < 2; ktile++) {
            floatx16 S;
#pragma unroll
            for (int i = 0; i < 16; i++) S[i] = 0.f;
            __builtin_amdgcn_s_setprio(1);
#pragma unroll
            for (int dc = 0; dc < 4; dc++) {
                short8 kf = *(const short8*)&Kt[cur][(ktile * 32 + ql) * 68 + dc * 16 + hi * 8];
                S = __builtin_amdgcn_mfma_f32_32x32x16_bf16(kf, qf[dc], S, 0, 0, 0);
            }
            __builtin_amdgcn_s_setprio(0);

            float e[16];
#pragma unroll
            for (int r = 0; r < 16; r++) e[r] = __expf(S[r]);
            float sa = (e[0] + e[1]) + (e[2] + e[3]);
            float sb = (e[4] + e[5]) + (e[6] + e[7]);
            float sc = (e[8] + e[9]) + (e[10] + e[11]);
            float sd = (e[12] + e[13]) + (e[14] + e[15]);
            lsum += (sa + sb) + (sc + sd);

#pragma unroll
            for (int p = 0; p < 2; p++) {
                unsigned cA = cvt_pk_bf16(e[8 * p + 0], e[8 * p + 1]);
                unsigned cC = cvt_pk_bf16(e[8 * p + 2], e[8 * p + 3]);
                unsigned cB = cvt_pk_bf16(e[8 * p + 4], e[8 * p + 5]);
                unsigned cD = cvt_pk_bf16(e[8 * p + 6], e[8 * p + 7]);
                uintx2 s02 = __builtin_amdgcn_permlane32_swap(cA, cB, false, false);
                uintx2 s13 = __builtin_amdgcn_permlane32_swap(cC, cD, false, false);
                union { unsigned u[4]; short8 s; } pf;
                pf.u[0] = s02[0]; pf.u[1] = s13[0];
                pf.u[2] = s02[1]; pf.u[3] = s13[1];
                const int kslot = ktile * 2 + p;
                __builtin_amdgcn_s_setprio(1);
#pragma unroll
                for (int dt = 0; dt < 2; dt++) {
                    short8 vf = *(const short8*)&Vt[cur][(dt * 32 + ql) * 68 + kslot * 16 + hi * 8];
                    accO[dt] = __builtin_amdgcn_mfma_f32_32x32x16_bf16(pf.s, vf, accO[dt], 0, 0, 0);
                }
                __builtin_amdgcn_s_setprio(0);
            }
        }
        // no end-of-iter barrier: next top-barrier separates buffer roles
    }

    lsum += __shfl_xor(lsum, 32);
    Ls[w][ql] = lsum;

    const int orow0 = b * 1024 + qt * 128 + w * 32;
#pragma unroll
    for (int g = 0; g < 4; g++) {
        floatx4 L4 = *(const floatx4*)&Ls[w][g * 8 + hi * 4];
#pragma unroll
        for (int rr = 0; rr < 4; rr++) {
            const float inv = 1.f / L4[rr];
            const int row = orow0 + g * 8 + hi * 4 + rr;
#pragma unroll
            for (int dt = 0; dt < 2; dt++)
                Out[(size_t)row * 1024 + h * 64 + dt * 32 + ql] =
                    f2bf(accO[dt][g * 4 + rr] * inv);
        }
    }
}

// ---------------------------------------------------------------------------
extern "C" void kernel_launch(void* const* d_in, const int* in_sizes, int n_in,
                              void* d_out, int out_size, void* d_ws, size_t ws_size,
                              hipStream_t stream) {
    const float* qx    = (const float*)d_in[0];
    const float* kvx   = (const float*)d_in[1];
    const float* qs    = (const float*)d_in[2];
    const float* kvs   = (const float*)d_in[3];
    const float* w_qx1 = (const float*)d_in[4];
    const float* w_qs1 = (const float*)d_in[5];
    const float* w_qx2 = (const float*)d_in[6];
    const float* w_qs2 = (const float*)d_in[7];
    const float* w_kvx = (const float*)d_in[8];
    const float* w_kvs = (const float*)d_in[9];
    const float* w_xp  = (const float*)d_in[10];
    const float* b_xp  = (const float*)d_in[11];
    const float* w_sp  = (const float*)d_in[12];
    const float* b_sp  = (const float*)d_in[13];
    float* out = (float*)d_out;
    (void)ws_size; (void)in_sizes; (void)n_in; (void)out_size;

    ushort* ws   = (ushort*)d_ws;
    ushort* Wb   = ws;
    ushort* q1q2 = ws + 4194304;
    ushort* Mbuf = ws + 12582912;
    ushort* kvpx = ws + 16777216;
    ushort* kvps = ws + 17301504;

    // 1) cast kv activations: kvx_b -> Mbuf, kvs_b -> q1q2 (both dead regions)
    CB c1; c1.src[0] = kvx; c1.dst[0] = Mbuf; c1.src[1] = kvs; c1.dst[1] = q1q2;
    castb<<<dim3(4096, 1, 2), 256, 0, stream>>>(c1);

    // 2) transpose kv + s-path Q weights into Wb
    TB tb1;
    tb1.src[0] = w_kvx; tb1.dst[0] = Wb;           tb1.K[0] = 1024; tb1.N[0] = 128;
    tb1.src[1] = w_kvs; tb1.dst[1] = Wb + 131072;  tb1.K[1] = 1024; tb1.N[1] = 128;
    tb1.src[2] = w_qs1; tb1.dst[2] = Wb + 262144;  tb1.K[2] = 1024; tb1.N[2] = 1024;
    tb1.src[3] = w_qs2; tb1.dst[3] = Wb + 1310720; tb1.K[3] = 1024; tb1.N[3] = 1024;
    tbatch<<<dim3(32, 32, 4), 256, 0, stream>>>(tb1);

    // 3) kv projections (z=2): K->Kp, V->Vt
    gemm_kv<<<dim3(32, 1, 2), 256, 0, stream>>>(
        Mbuf, q1q2, Wb, Wb + 131072, kvpx, kvps, kvpx + 262144, kvps + 262144);

    // 4) cast qs -> Mbuf (kvx_b dead)
    CB c2; c2.src[0] = qs; c2.dst[0] = Mbuf; c2.src[1] = qs; c2.dst[1] = Mbuf;
    castb<<<dim3(4096, 1, 1), 256, 0, stream>>>(c2);

    // 5) s-path Q GEMM: q1s|q2s -> q1q2 (kvs_b dead), scale 1/8 folded
    gemm_q<<<dim3(32, 32), 256, 0, stream>>>(Mbuf, Wb + 262144, q1q2, 0.125f);

    // 6) s attention: M_s -> Mbuf (qs_b dead), M_sx -> d_out lo (bf16 scratch)
    attn_kernel<<<dim3(8, 16, 8), 256, 0, stream>>>(q1q2, kvps, kvpx, Mbuf, (ushort*)out);

    // 7) transpose sp + x-path Q weights (Wt_kv/Wt_qs dead)
    TB tb2;
    tb2.src[0] = w_sp;  tb2.dst[0] = Wb;           tb2.K[0] = 2048; tb2.N[0] = 1024;
    tb2.src[1] = w_qx1; tb2.dst[1] = Wb + 2097152; tb2.K[1] = 1024; tb2.N[1] = 1024;
    tb2.src[2] = w_qx2; tb2.dst[2] = Wb + 3145728; tb2.K[2] = 1024; tb2.N[2] = 1024;
    tb2.src[3] = w_sp;  tb2.dst[3] = Wb;           tb2.K[3] = 0;    tb2.N[3] = 0;
    tbatch<<<dim3(64, 32, 3), 256, 0, stream>>>(tb2);

    // 8) s_out = [M_sx | M_s] @ Wsp^T + b_sp -> d_out hi (fp32)
    gemm_proj<<<dim3(32, 16), 256, 0, stream>>>((ushort*)out, Mbuf, Wb, b_sp, out + 4194304);

    // 9) cast qx -> Mbuf (M_s dead)
    CB c3; c3.src[0] = qx; c3.dst[0] = Mbuf; c3.src[1] = qx; c3.dst[1] = Mbuf;
    castb<<<dim3(4096, 1, 1), 256, 0, stream>>>(c3);

    // 10) x-path Q GEMM -> q1q2 (dead after s-attn)
    gemm_q<<<dim3(32, 32), 256, 0, stream>>>(Mbuf, Wb + 2097152, q1q2, 0.125f);

    // 11) x attention: M_x -> Mbuf (qx_b dead), M_xs -> Wb (weights dead)
    attn_kernel<<<dim3(8, 16, 8), 256, 0, stream>>>(q1q2, kvpx, kvps, Mbuf, Wb);

    // 12) transpose xp -> q1q2 (dead after x-attn)
    TB tb3;
    tb3.src[0] = w_xp; tb3.dst[0] = q1q2; tb3.K[0] = 2048; tb3.N[0] = 1024;
    tb3.src[1] = w_xp; tb3.dst[1] = q1q2; tb3.K[1] = 0;    tb3.N[1] = 0;
    tb3.src[2] = w_xp; tb3.dst[2] = q1q2; tb3.K[2] = 0;    tb3.N[2] = 0;
    tb3.src[3] = w_xp; tb3.dst[3] = q1q2; tb3.K[3] = 0;    tb3.N[3] = 0;
    tbatch<<<dim3(64, 32, 1), 256, 0, stream>>>(tb3);

    // 13) x_out = [M_xs | M_x] @ Wxp^T + b_xp -> d_out lo (M_sx scratch dead)
    gemm_proj<<<dim3(32, 16), 256, 0, stream>>>(Wb, Mbuf, q1q2, b_xp, out);
}

// Round 13
// 410.741 us; speedup vs baseline: 1.0627x; 1.0071x over previous
//
#include <hip/hip_runtime.h>
#include <hip/hip_bf16.h>

// ---------------------------------------------------------------------------
// RecurrentAttention: B=4, L=1024, D_MODEL=1024, N_HEAD=16, D_HEAD=64
// Inputs/outputs fp32; internals bf16, fp32 accumulate.
//
// ws (bf16-el units, 35.65 MB proven-safe):
//   Wb    [0, 4194304)         weights rotate -> M_xs (x-attn OutB)
//   q1q2  [4194304, 12582912)  kvs_b -> Q outputs [4096x2048] -> Wt_xp
//   Mbuf  [12582912, 16777216) kvx_b -> qs_b -> M_s -> qx_b -> M_x
//   kvpx  [16777216,+524288)   Kp [4096x64] + Vt [4][64][1024]
//   kvps  [17301504,+524288)
// d_out lo = bf16 scratch for M_sx (dead before final x_out write).
// All launches sequential on one stream -> aliasing race-free.
//
// v13 (R12 post-mortem: attn 50.2us ea, VALU 44% > MFMA 27% -> shift work
// VALU->MFMA): lsum via ones-MFMA — accO2 = mfma(pf, ones) accumulates
// row-sums of P in the SAME C-layout as accO (constant B => layout-proof),
// eliminating the 30 adds/iter + shfl_xor + Ls LDS transpose. Epilogue
// divide is same-lane. attn v9; GEMMs unchanged (R8-proven).
// ---------------------------------------------------------------------------

typedef short short8 __attribute__((ext_vector_type(8)));
typedef short short4v __attribute__((ext_vector_type(4)));
typedef float floatx4 __attribute__((ext_vector_type(4)));
typedef float floatx16 __attribute__((ext_vector_type(16)));
typedef unsigned uintx2 __attribute__((ext_vector_type(2)));

__device__ __forceinline__ float b2f(ushort h) {
    union { unsigned u; float f; } v; v.u = ((unsigned)h) << 16; return v.f;
}
__device__ __forceinline__ ushort f2bf(float f) {
    union { float f; unsigned u; } v; v.f = f;
    return (ushort)((v.u + 0x7FFFu + ((v.u >> 16) & 1u)) >> 16);
}
__device__ __forceinline__ unsigned cvt_pk_bf16(float lo, float hi) {
    unsigned r;
    asm("v_cvt_pk_bf16_f32 %0, %1, %2" : "=v"(r) : "v"(lo), "v"(hi));
    return r;
}
__device__ __forceinline__ void gl_lds16(const ushort* g, ushort* l) {
    __builtin_amdgcn_global_load_lds(
        (const __attribute__((address_space(1))) void*)g,
        (__attribute__((address_space(3))) void*)l, 16, 0, 0);
}

// ---------------------------------------------------------------------------
// Batched fp32 -> bf16 cast. grid (4096, 1, nz), block 256: 4 el/thread.
// ---------------------------------------------------------------------------
struct CB { const float* src[2]; ushort* dst[2]; };

__global__ __launch_bounds__(256) void castb(CB cb) {
    const int z = blockIdx.z;
    const float* s = cb.src[z];
    ushort* d = cb.dst[z];
    const size_t i = ((size_t)blockIdx.x * 256 + threadIdx.x) * 4;
    floatx4 f = *(const floatx4*)&s[i];
    short4v o;
#pragma unroll
    for (int k = 0; k < 4; k++) o[k] = (short)f2bf(f[k]);
    *(short4v*)&d[i] = o;
}

// ---------------------------------------------------------------------------
// Batched fp32->bf16 weight transpose: Wt[n*K+k] = bf16(W[k*N+n])
// ---------------------------------------------------------------------------
struct TB { const float* src[4]; ushort* dst[4]; int K[4]; int N[4]; };

__global__ __launch_bounds__(256) void tbatch(TB tb) {
    __shared__ float tile[32][33];
    const int wi = blockIdx.z;
    const int K = tb.K[wi], N = tb.N[wi];
    const int k0 = blockIdx.x * 32, n0 = blockIdx.y * 32;
    if (k0 >= K || n0 >= N) return;
    const float* W = tb.src[wi];
    ushort* Wt = tb.dst[wi];
    const int tx = threadIdx.x & 31, ty = threadIdx.x >> 5;
#pragma unroll
    for (int i = ty; i < 32; i += 8)
        tile[i][tx] = W[(size_t)(k0 + i) * N + n0 + tx];
    __syncthreads();
#pragma unroll
    for (int i = ty; i < 32; i += 8)
        Wt[(size_t)(n0 + i) * K + k0 + tx] = f2bf(tile[tx][i]);
}

// ---------------------------------------------------------------------------
// Q-GEMM, 128x64 tile, BK=64 (R8 proven): C = cscale*(A[4096x1024] @ Bt^T),
// Bt [2048][1024], C bf16 ldc=2048. grid (32, 32) = 1024 blocks = 4/CU.
// Twin K=32 sub-tiles per barrier pair -> 16 MFMA / 2 barriers. LDS 24KB.
// ---------------------------------------------------------------------------
__global__ __launch_bounds__(256) void gemm_q(
    const ushort* __restrict__ A, const ushort* __restrict__ Bt,
    ushort* __restrict__ C, float cscale)
{
    __shared__ ushort As0[128 * 32];
    __shared__ ushort As1[128 * 32];
    __shared__ ushort Bs0[64 * 32];
    __shared__ ushort Bs1[64 * 32];
    const int t = threadIdx.x;
    const int lane = t & 63, w = t >> 6;
    const int q = lane >> 4, li = lane & 15;
    const int rowA = blockIdx.x * 128, colB = blockIdx.y * 64;
    const int ar = rowA + w * 32 + (lane >> 2);
    const int br = colB + w * 16 + (lane >> 2);
    const int cl = (lane & 3) * 8;
    ushort* adst0 = &As0[w * 32 * 32];
    ushort* adst1 = &As1[w * 32 * 32];
    ushort* bdst0 = &Bs0[w * 16 * 32];
    ushort* bdst1 = &Bs1[w * 16 * 32];

    floatx4 acc[2][4];
    const floatx4 z4 = {0.f, 0.f, 0.f, 0.f};
#pragma unroll
    for (int i = 0; i < 2; i++)
#pragma unroll
        for (int j = 0; j < 4; j++) acc[i][j] = z4;

    for (int k0 = 0; k0 < 1024; k0 += 64) {
        gl_lds16(A + (size_t)ar * 1024 + k0 + cl, adst0);
        gl_lds16(A + (size_t)(ar + 16) * 1024 + k0 + cl, adst0 + 16 * 32);
        gl_lds16(A + (size_t)ar * 1024 + k0 + 32 + cl, adst1);
        gl_lds16(A + (size_t)(ar + 16) * 1024 + k0 + 32 + cl, adst1 + 16 * 32);
        gl_lds16(Bt + (size_t)br * 1024 + k0 + cl, bdst0);
        gl_lds16(Bt + (size_t)br * 1024 + k0 + 32 + cl, bdst1);
        __syncthreads();
        short8 af[2], bf[4];
#pragma unroll
        for (int i = 0; i < 2; i++) af[i] = *(const short8*)&As0[(w * 32 + i * 16 + li) * 32 + q * 8];
#pragma unroll
        for (int j = 0; j < 4; j++) bf[j] = *(const short8*)&Bs0[(j * 16 + li) * 32 + q * 8];
#pragma unroll
        for (int i = 0; i < 2; i++)
#pragma unroll
            for (int j = 0; j < 4; j++)
                acc[i][j] = __builtin_amdgcn_mfma_f32_16x16x32_bf16(af[i], bf[j], acc[i][j], 0, 0, 0);
#pragma unroll
        for (int i = 0; i < 2; i++) af[i] = *(const short8*)&As1[(w * 32 + i * 16 + li) * 32 + q * 8];
#pragma unroll
        for (int j = 0; j < 4; j++) bf[j] = *(const short8*)&Bs1[(j * 16 + li) * 32 + q * 8];
#pragma unroll
        for (int i = 0; i < 2; i++)
#pragma unroll
            for (int j = 0; j < 4; j++)
                acc[i][j] = __builtin_amdgcn_mfma_f32_16x16x32_bf16(af[i], bf[j], acc[i][j], 0, 0, 0);
        __syncthreads();
    }
#pragma unroll
    for (int i = 0; i < 2; i++) {
        const int rowb = rowA + w * 32 + i * 16 + q * 4;
#pragma unroll
        for (int j = 0; j < 4; j++) {
            const int col = colB + j * 16 + li;
#pragma unroll
            for (int r = 0; r < 4; r++)
                C[(size_t)(rowb + r) * 2048 + col] = f2bf(acc[i][j][r] * cscale);
        }
    }
}

// ---------------------------------------------------------------------------
// KV-GEMM (z=2 batched): C = A[4096x1024] @ Bt[128][1024]^T; epilogue splits
// cols 0-63 -> Kp[row*64+col], 64-127 -> Vt[b][d][tok]. grid (32,1,2).
// ---------------------------------------------------------------------------
__global__ __launch_bounds__(256) void gemm_kv(
    const ushort* __restrict__ A0, const ushort* __restrict__ A1,
    const ushort* __restrict__ B0, const ushort* __restrict__ B1,
    ushort* __restrict__ C0, ushort* __restrict__ C1,
    ushort* __restrict__ vt0, ushort* __restrict__ vt1)
{
    __shared__ ushort As[128 * 32];
    __shared__ ushort Bs[128 * 32];
    const int z = blockIdx.z;
    const ushort* A = z ? A1 : A0;
    const ushort* Bt = z ? B1 : B0;
    ushort* Kp = z ? C1 : C0;
    ushort* vt = z ? vt1 : vt0;

    const int t = threadIdx.x;
    const int lane = t & 63, w = t >> 6;
    const int q = lane >> 4, li = lane & 15;
    const int wr = (w >> 1) * 64, wc = (w & 1) * 64;
    const int rowA = blockIdx.x * 128;
    const int ar = rowA + w * 32 + (lane >> 2);
    const int br = w * 32 + (lane >> 2);
    const int cl = (lane & 3) * 8;
    ushort* adst = &As[w * 32 * 32];
    ushort* bdst = &Bs[w * 32 * 32];

    floatx4 acc[4][4];
    const floatx4 z4 = {0.f, 0.f, 0.f, 0.f};
#pragma unroll
    for (int i = 0; i < 4; i++)
#pragma unroll
        for (int j = 0; j < 4; j++) acc[i][j] = z4;

    for (int k0 = 0; k0 < 1024; k0 += 32) {
        gl_lds16(A + (size_t)ar * 1024 + k0 + cl, adst);
        gl_lds16(A + (size_t)(ar + 16) * 1024 + k0 + cl, adst + 16 * 32);
        gl_lds16(Bt + (size_t)br * 1024 + k0 + cl, bdst);
        gl_lds16(Bt + (size_t)(br + 16) * 1024 + k0 + cl, bdst + 16 * 32);
        __syncthreads();
        short8 af[4], bf[4];
#pragma unroll
        for (int i = 0; i < 4; i++) af[i] = *(const short8*)&As[(wr + i * 16 + li) * 32 + q * 8];
#pragma unroll
        for (int j = 0; j < 4; j++) bf[j] = *(const short8*)&Bs[(wc + j * 16 + li) * 32 + q * 8];
#pragma unroll
        for (int i = 0; i < 4; i++)
#pragma unroll
            for (int j = 0; j < 4; j++)
                acc[i][j] = __builtin_amdgcn_mfma_f32_16x16x32_bf16(af[i], bf[j], acc[i][j], 0, 0, 0);
        __syncthreads();
    }
#pragma unroll
    for (int i = 0; i < 4; i++) {
        const int rowb = rowA + wr + i * 16 + q * 4;
#pragma unroll
        for (int j = 0; j < 4; j++) {
            const int col = wc + j * 16 + li;
#pragma unroll
            for (int r = 0; r < 4; r++) {
                const int row = rowb + r;
                const ushort vb = f2bf(acc[i][j][r]);
                if (col < 64) Kp[(size_t)row * 64 + col] = vb;
                else vt[((row >> 10) << 16) + ((col - 64) << 10) + (row & 1023)] = vb;
            }
        }
    }
}

// ---------------------------------------------------------------------------
// Fused concat-projection GEMM, 128x64 tile, BK=64 (R8 proven), K=2048:
// C = [A1|A2] @ Bt^T + bias (fp32 out). grid (32, 16) = 512 blocks = 2/CU.
// ---------------------------------------------------------------------------
__global__ __launch_bounds__(256) void gemm_proj(
    const ushort* __restrict__ A1, const ushort* __restrict__ A2,
    const ushort* __restrict__ Bt, const float* __restrict__ bias,
    float* __restrict__ C)
{
    __shared__ ushort As0[128 * 32];
    __shared__ ushort As1[128 * 32];
    __shared__ ushort Bs0[64 * 32];
    __shared__ ushort Bs1[64 * 32];
    const int t = threadIdx.x;
    const int lane = t & 63, w = t >> 6;
    const int q = lane >> 4, li = lane & 15;
    const int rowA = blockIdx.x * 128, colB = blockIdx.y * 64;
    const int ar = rowA + w * 32 + (lane >> 2);
    const int br = colB + w * 16 + (lane >> 2);
    const int cl = (lane & 3) * 8;
    ushort* adst0 = &As0[w * 32 * 32];
    ushort* adst1 = &As1[w * 32 * 32];
    ushort* bdst0 = &Bs0[w * 16 * 32];
    ushort* bdst1 = &Bs1[w * 16 * 32];

    floatx4 acc[2][4];
    const floatx4 z4 = {0.f, 0.f, 0.f, 0.f};
#pragma unroll
    for (int i = 0; i < 2; i++)
#pragma unroll
        for (int j = 0; j < 4; j++) acc[i][j] = z4;

    for (int k0 = 0; k0 < 2048; k0 += 64) {
        const ushort* Ap = (k0 < 1024) ? A1 : A2;
        const int kc = k0 & 1023;
        const int kp0 = kc + cl;
        const int kp1 = kc + 32 + cl;
        const int koff = (k0 >= 1024) ? 64 : 0;
        const int ks0 = ((kp0 >> 6) << 7) + (kp0 & 63) + koff;
        const int ks1 = ((kp1 >> 6) << 7) + (kp1 & 63) + koff;
        gl_lds16(Ap + (size_t)ar * 1024 + kc + cl, adst0);
        gl_lds16(Ap + (size_t)(ar + 16) * 1024 + kc + cl, adst0 + 16 * 32);
        gl_lds16(Ap + (size_t)ar * 1024 + kc + 32 + cl, adst1);
        gl_lds16(Ap + (size_t)(ar + 16) * 1024 + kc + 32 + cl, adst1 + 16 * 32);
        gl_lds16(Bt + (size_t)br * 2048 + ks0, bdst0);
        gl_lds16(Bt + (size_t)br * 2048 + ks1, bdst1);
        __syncthreads();
        short8 af[2], bf[4];
#pragma unroll
        for (int i = 0; i < 2; i++) af[i] = *(const short8*)&As0[(w * 32 + i * 16 + li) * 32 + q * 8];
#pragma unroll
        for (int j = 0; j < 4; j++) bf[j] = *(const short8*)&Bs0[(j * 16 + li) * 32 + q * 8];
#pragma unroll
        for (int i = 0; i < 2; i++)
#pragma unroll
            for (int j = 0; j < 4; j++)
                acc[i][j] = __builtin_amdgcn_mfma_f32_16x16x32_bf16(af[i], bf[j], acc[i][j], 0, 0, 0);
#pragma unroll
        for (int i = 0; i < 2; i++) af[i] = *(const short8*)&As1[(w * 32 + i * 16 + li) * 32 + q * 8];
#pragma unroll
        for (int j = 0; j < 4; j++) bf[j] = *(const short8*)&Bs1[(j * 16 + li) * 32 + q * 8];
#pragma unroll
        for (int i = 0; i < 2; i++)
#pragma unroll
            for (int j = 0; j < 4; j++)
                acc[i][j] = __builtin_amdgcn_mfma_f32_16x16x32_bf16(af[i], bf[j], acc[i][j], 0, 0, 0);
        __syncthreads();
    }
#pragma unroll
    for (int i = 0; i < 2; i++) {
        const int rowb = rowA + w * 32 + i * 16 + q * 4;
#pragma unroll
        for (int j = 0; j < 4; j++) {
            const int col = colB + j * 16 + li;
            const float bv = bias[col];
#pragma unroll
            for (int r = 0; r < 4; r++)
                C[(size_t)(rowb + r) * 1024 + col] = acc[i][j][r] + bv;
        }
    }
}

// ---------------------------------------------------------------------------
// Flash attention v9: v8 (branch-free 1-barrier dbuf) + lsum-via-ones-MFMA.
// accO2 = mfma(pf, ones_bf16) accumulates row-sums of P in the same C-layout
// as accO (constant B operand => layout-proof). Epilogue: same-lane divide.
// Removes lsum add-tree, shfl_xor, and Ls LDS transpose. grid (8,16,8).
// ---------------------------------------------------------------------------
__global__ __launch_bounds__(256, 4) void attn_kernel(
    const ushort* __restrict__ Qbase,
    const ushort* __restrict__ KVa, const ushort* __restrict__ KVb,
    ushort* __restrict__ OutA, ushort* __restrict__ OutB)
{
    __shared__ ushort Kt[2][64 * 68];   // [buf][key][d]
    __shared__ ushort Vt[2][64 * 68];   // [buf][d][key]

    const int t = threadIdx.x;
    const int lane = t & 63, w = t >> 6;
    const int ql = lane & 31, hi = lane >> 5;
    const int qt = blockIdx.x, h = blockIdx.y;
    const int z = blockIdx.z, b = z >> 1, a2 = z & 1;

    const ushort* Q  = Qbase + (a2 ? 1024 : 0);
    const ushort* KV = a2 ? KVb : KVa;
    ushort* Out      = a2 ? OutB : OutA;
    const ushort* Kp = KV;
    const ushort* Vg = KV + 262144;

    const size_t qrow = (size_t)(b * 1024 + qt * 128 + w * 32 + ql);
    short8 qf[4];
#pragma unroll
    for (int dc = 0; dc < 4; dc++)
        qf[dc] = *(const short8*)&Q[qrow * 2048 + h * 64 + dc * 16 + hi * 8];

    floatx16 accO[2], accO2;
#pragma unroll
    for (int dt = 0; dt < 2; dt++)
#pragma unroll
        for (int i = 0; i < 16; i++) accO[dt][i] = 0.f;
#pragma unroll
    for (int i = 0; i < 16; i++) accO2[i] = 0.f;

    // bf16 1.0 broadcast B-operand (constant -> fragment-layout irrelevant)
    short8 one8;
#pragma unroll
    for (int i = 0; i < 8; i++) one8[i] = (short)0x3F80;

    const int srow = t >> 2, sch = (t & 3) * 16;
    const ushort* ksrc0 = &Kp[(size_t)(b * 1024 + srow) * 64 + sch];
    const ushort* vsrc0 = &Vg[(size_t)(b * 64 + srow) * 1024 + sch];
    const int soff = srow * 68 + sch;

    short8 kreg[2], vreg[2];
    // prologue: tile 0 -> regs -> buf0; tile 1 -> regs
#pragma unroll
    for (int i = 0; i < 2; i++) {
        kreg[i] = *(const short8*)&ksrc0[i * 8];
        vreg[i] = *(const short8*)&vsrc0[i * 8];
    }
#pragma unroll
    for (int i = 0; i < 2; i++) {
        *(short8*)&Kt[0][soff + i * 8] = kreg[i];
        *(short8*)&Vt[0][soff + i * 8] = vreg[i];
    }
#pragma unroll
    for (int i = 0; i < 2; i++) {
        kreg[i] = *(const short8*)&ksrc0[64 * 64 + i * 8];
        vreg[i] = *(const short8*)&vsrc0[64 + i * 8];
    }

    for (int kt = 0; kt < 16; kt++) {
        const int cur = kt & 1;
        __syncthreads();   // buf[cur] writes visible; buf[cur^1] readers done

        // unconditional: write tile kt+1 into buf[cur^1]
        // (kt=15: rewrites tile-15 data into the dead buffer — never read)
#pragma unroll
        for (int i = 0; i < 2; i++) {
            *(short8*)&Kt[cur ^ 1][soff + i * 8] = kreg[i];
            *(short8*)&Vt[cur ^ 1][soff + i * 8] = vreg[i];
        }
        // unconditional clamped prefetch of tile min(kt+2,15); values of the
        // clamped iterations are never consumed (branch-free -> no spills)
        {
            const int nt = (kt + 2 > 15) ? 15 : (kt + 2);
            const ushort* ksrc = ksrc0 + (size_t)nt * 64 * 64;
            const ushort* vsrc = vsrc0 + nt * 64;
#pragma unroll
            for (int i = 0; i < 2; i++) {
                kreg[i] = *(const short8*)&ksrc[i * 8];
                vreg[i] = *(const short8*)&vsrc[i * 8];
            }
        }

#pragma unroll
        for (int ktile = 0; ktile < 2; ktile++) {
            floatx16 S;
#pragma unroll
            for (int i = 0; i < 16; i++) S[i] = 0.f;
            __builtin_amdgcn_s_setprio(1);
#pragma unroll
            for (int dc = 0; dc < 4; dc++) {
                short8 kf = *(const short8*)&Kt[cur][(ktile * 32 + ql) * 68 + dc * 16 + hi * 8];
                S = __builtin_amdgcn_mfma_f32_32x32x16_bf16(kf, qf[dc], S, 0, 0, 0);
            }
            __builtin_amdgcn_s_setprio(0);

            float e[16];
#pragma unroll
            for (int r = 0; r < 16; r++) e[r] = __expf(S[r]);

#pragma unroll
            for (int p = 0; p < 2; p++) {
                unsigned cA = cvt_pk_bf16(e[8 * p + 0], e[8 * p + 1]);
                unsigned cC = cvt_pk_bf16(e[8 * p + 2], e[8 * p + 3]);
                unsigned cB = cvt_pk_bf16(e[8 * p + 4], e[8 * p + 5]);
                unsigned cD = cvt_pk_bf16(e[8 * p + 6], e[8 * p + 7]);
                uintx2 s02 = __builtin_amdgcn_permlane32_swap(cA, cB, false, false);
                uintx2 s13 = __builtin_amdgcn_permlane32_swap(cC, cD, false, false);
                union { unsigned u[4]; short8 s; } pf;
                pf.u[0] = s02[0]; pf.u[1] = s13[0];
                pf.u[2] = s02[1]; pf.u[3] = s13[1];
                const int kslot = ktile * 2 + p;
                __builtin_amdgcn_s_setprio(1);
#pragma unroll
                for (int dt = 0; dt < 2; dt++) {
                    short8 vf = *(const short8*)&Vt[cur][(dt * 32 + ql) * 68 + kslot * 16 + hi * 8];
                    accO[dt] = __builtin_amdgcn_mfma_f32_32x32x16_bf16(pf.s, vf, accO[dt], 0, 0, 0);
                }
                // lsum: row-sums of P, same C-layout as accO (ones B-operand)
                accO2 = __builtin_amdgcn_mfma_f32_32x32x16_bf16(pf.s, one8, accO2, 0, 0, 0);
                __builtin_amdgcn_s_setprio(0);
            }
        }
        // no end-of-iter barrier: next top-barrier separates buffer roles
    }

    const int orow0 = b * 1024 + qt * 128 + w * 32;
#pragma unroll
    for (int g = 0; g < 4; g++) {
#pragma unroll
        for (int rr = 0; rr < 4; rr++) {
            const float inv = 1.f / accO2[g * 4 + rr];   // same-lane lsum
            const int row = orow0 + g * 8 + hi * 4 + rr;
#pragma unroll
            for (int dt = 0; dt < 2; dt++)
                Out[(size_t)row * 1024 + h * 64 + dt * 32 + ql] =
                    f2bf(accO[dt][g * 4 + rr] * inv);
        }
    }
}

// ---------------------------------------------------------------------------
extern "C" void kernel_launch(void* const* d_in, const int* in_sizes, int n_in,
                              void* d_out, int out_size, void* d_ws, size_t ws_size,
                              hipStream_t stream) {
    const float* qx    = (const float*)d_in[0];
    const float* kvx   = (const float*)d_in[1];
    const float* qs    = (const float*)d_in[2];
    const float* kvs   = (const float*)d_in[3];
    const float* w_qx1 = (const float*)d_in[4];
    const float* w_qs1 = (const float*)d_in[5];
    const float* w_qx2 = (const float*)d_in[6];
    const float* w_qs2 = (const float*)d_in[7];
    const float* w_kvx = (const float*)d_in[8];
    const float* w_kvs = (const float*)d_in[9];
    const float* w_xp  = (const float*)d_in[10];
    const float* b_xp  = (const float*)d_in[11];
    const float* w_sp  = (const float*)d_in[12];
    const float* b_sp  = (const float*)d_in[13];
    float* out = (float*)d_out;
    (void)ws_size; (void)in_sizes; (void)n_in; (void)out_size;

    ushort* ws   = (ushort*)d_ws;
    ushort* Wb   = ws;
    ushort* q1q2 = ws + 4194304;
    ushort* Mbuf = ws + 12582912;
    ushort* kvpx = ws + 16777216;
    ushort* kvps = ws + 17301504;

    // 1) cast kv activations: kvx_b -> Mbuf, kvs_b -> q1q2 (both dead regions)
    CB c1; c1.src[0] = kvx; c1.dst[0] = Mbuf; c1.src[1] = kvs; c1.dst[1] = q1q2;
    castb<<<dim3(4096, 1, 2), 256, 0, stream>>>(c1);

    // 2) transpose kv + s-path Q weights into Wb
    TB tb1;
    tb1.src[0] = w_kvx; tb1.dst[0] = Wb;           tb1.K[0] = 1024; tb1.N[0] = 128;
    tb1.src[1] = w_kvs; tb1.dst[1] = Wb + 131072;  tb1.K[1] = 1024; tb1.N[1] = 128;
    tb1.src[2] = w_qs1; tb1.dst[2] = Wb + 262144;  tb1.K[2] = 1024; tb1.N[2] = 1024;
    tb1.src[3] = w_qs2; tb1.dst[3] = Wb + 1310720; tb1.K[3] = 1024; tb1.N[3] = 1024;
    tbatch<<<dim3(32, 32, 4), 256, 0, stream>>>(tb1);

    // 3) kv projections (z=2): K->Kp, V->Vt
    gemm_kv<<<dim3(32, 1, 2), 256, 0, stream>>>(
        Mbuf, q1q2, Wb, Wb + 131072, kvpx, kvps, kvpx + 262144, kvps + 262144);

    // 4) cast qs -> Mbuf (kvx_b dead)
    CB c2; c2.src[0] = qs; c2.dst[0] = Mbuf; c2.src[1] = qs; c2.dst[1] = Mbuf;
    castb<<<dim3(4096, 1, 1), 256, 0, stream>>>(c2);

    // 5) s-path Q GEMM: q1s|q2s -> q1q2 (kvs_b dead), scale 1/8 folded
    gemm_q<<<dim3(32, 32), 256, 0, stream>>>(Mbuf, Wb + 262144, q1q2, 0.125f);

    // 6) s attention: M_s -> Mbuf (qs_b dead), M_sx -> d_out lo (bf16 scratch)
    attn_kernel<<<dim3(8, 16, 8), 256, 0, stream>>>(q1q2, kvps, kvpx, Mbuf, (ushort*)out);

    // 7) transpose sp + x-path Q weights (Wt_kv/Wt_qs dead)
    TB tb2;
    tb2.src[0] = w_sp;  tb2.dst[0] = Wb;           tb2.K[0] = 2048; tb2.N[0] = 1024;
    tb2.src[1] = w_qx1; tb2.dst[1] = Wb + 2097152; tb2.K[1] = 1024; tb2.N[1] = 1024;
    tb2.src[2] = w_qx2; tb2.dst[2] = Wb + 3145728; tb2.K[2] = 1024; tb2.N[2] = 1024;
    tb2.src[3] = w_sp;  tb2.dst[3] = Wb;           tb2.K[3] = 0;    tb2.N[3] = 0;
    tbatch<<<dim3(64, 32, 3), 256, 0, stream>>>(tb2);

    // 8) s_out = [M_sx | M_s] @ Wsp^T + b_sp -> d_out hi (fp32)
    gemm_proj<<<dim3(32, 16), 256, 0, stream>>>((ushort*)out, Mbuf, Wb, b_sp, out + 4194304);

    // 9) cast qx -> Mbuf (M_s dead)
    CB c3; c3.src[0] = qx; c3.dst[0] = Mbuf; c3.src[1] = qx; c3.dst[1] = Mbuf;
    castb<<<dim3(4096, 1, 1), 256, 0, stream>>>(c3);

    // 10) x-path Q GEMM -> q1q2 (dead after s-attn)
    gemm_q<<<dim3(32, 32), 256, 0, stream>>>(Mbuf, Wb + 2097152, q1q2, 0.125f);

    // 11) x attention: M_x -> Mbuf (qx_b dead), M_xs -> Wb (weights dead)
    attn_kernel<<<dim3(8, 16, 8), 256, 0, stream>>>(q1q2, kvpx, kvps, Mbuf, Wb);

    // 12) transpose xp -> q1q2 (dead after x-attn)
    TB tb3;
    tb3.src[0] = w_xp; tb3.dst[0] = q1q2; tb3.K[0] = 2048; tb3.N[0] = 1024;
    tb3.src[1] = w_xp; tb3.dst[1] = q1q2; tb3.K[1] = 0;    tb3.N[1] = 0;
    tb3.src[2] = w_xp; tb3.dst[2] = q1q2; tb3.K[2] = 0;    tb3.N[2] = 0;
    tb3.src[3] = w_xp; tb3.dst[3] = q1q2; tb3.K[3] = 0;    tb3.N[3] = 0;
    tbatch<<<dim3(64, 32, 1), 256, 0, stream>>>(tb3);

    // 13) x_out = [M_xs | M_x] @ Wxp^T + b_xp -> d_out lo (M_sx scratch dead)
    gemm_proj<<<dim3(32, 16), 256, 0, stream>>>(Wb, Mbuf, q1q2, b_xp, out);
}

// Round 14
// 399.673 us; speedup vs baseline: 1.0922x; 1.0277x over previous
//
#include <hip/hip_runtime.h>
#include <hip/hip_bf16.h>

// ---------------------------------------------------------------------------
// RecurrentAttention: B=4, L=1024, D_MODEL=1024, N_HEAD=16, D_HEAD=64
// Inputs/outputs fp32; internals bf16, fp32 accumulate.
//
// ws (bf16-el units, 35.65 MB proven-safe):
//   Wb    [0, 4194304)         weights rotate -> M_xs (x-attn OutB)
//   q1q2  [4194304, 12582912)  kvs_b -> Q outputs [4096x2048] -> Wt_xp
//   Mbuf  [12582912, 16777216) kvx_b -> qs_b -> M_s -> qx_b -> M_x
//   kvpx  [16777216,+524288)   Kp [4096x64] + Vt [4][64][1024]
//   kvps  [17301504,+524288)
// d_out lo = bf16 scratch for M_sx (dead before final x_out write).
// All launches sequential on one stream -> aliasing race-free.
//
// v14 (R13 post-mortem: attn pinned at 50.4us, MFMA 35% + VALU 41% ~ 76%
// combined -> serial chain-bound, not pipe-bound). attn v10: the two
// ktiles' S-chains (S0, S1) computed as INTERLEAVED independent 4-MFMA
// chains; S1 stays live through ktile0's exp/pack/PV so VALU work overlaps
// the S1 chain tail. +16 VGPR (occupancy grid-capped, free).
// GEMMs unchanged (R8-proven). Ones-MFMA lsum kept (R13, layout-proof).
// ---------------------------------------------------------------------------

typedef short short8 __attribute__((ext_vector_type(8)));
typedef short short4v __attribute__((ext_vector_type(4)));
typedef float floatx4 __attribute__((ext_vector_type(4)));
typedef float floatx16 __attribute__((ext_vector_type(16)));
typedef unsigned uintx2 __attribute__((ext_vector_type(2)));

__device__ __forceinline__ float b2f(ushort h) {
    union { unsigned u; float f; } v; v.u = ((unsigned)h) << 16; return v.f;
}
__device__ __forceinline__ ushort f2bf(float f) {
    union { float f; unsigned u; } v; v.f = f;
    return (ushort)((v.u + 0x7FFFu + ((v.u >> 16) & 1u)) >> 16);
}
__device__ __forceinline__ unsigned cvt_pk_bf16(float lo, float hi) {
    unsigned r;
    asm("v_cvt_pk_bf16_f32 %0, %1, %2" : "=v"(r) : "v"(lo), "v"(hi));
    return r;
}
__device__ __forceinline__ void gl_lds16(const ushort* g, ushort* l) {
    __builtin_amdgcn_global_load_lds(
        (const __attribute__((address_space(1))) void*)g,
        (__attribute__((address_space(3))) void*)l, 16, 0, 0);
}

// ---------------------------------------------------------------------------
// Batched fp32 -> bf16 cast. grid (4096, 1, nz), block 256: 4 el/thread.
// ---------------------------------------------------------------------------
struct CB { const float* src[2]; ushort* dst[2]; };

__global__ __launch_bounds__(256) void castb(CB cb) {
    const int z = blockIdx.z;
    const float* s = cb.src[z];
    ushort* d = cb.dst[z];
    const size_t i = ((size_t)blockIdx.x * 256 + threadIdx.x) * 4;
    floatx4 f = *(const floatx4*)&s[i];
    short4v o;
#pragma unroll
    for (int k = 0; k < 4; k++) o[k] = (short)f2bf(f[k]);
    *(short4v*)&d[i] = o;
}

// ---------------------------------------------------------------------------
// Batched fp32->bf16 weight transpose: Wt[n*K+k] = bf16(W[k*N+n])
// ---------------------------------------------------------------------------
struct TB { const float* src[4]; ushort* dst[4]; int K[4]; int N[4]; };

__global__ __launch_bounds__(256) void tbatch(TB tb) {
    __shared__ float tile[32][33];
    const int wi = blockIdx.z;
    const int K = tb.K[wi], N = tb.N[wi];
    const int k0 = blockIdx.x * 32, n0 = blockIdx.y * 32;
    if (k0 >= K || n0 >= N) return;
    const float* W = tb.src[wi];
    ushort* Wt = tb.dst[wi];
    const int tx = threadIdx.x & 31, ty = threadIdx.x >> 5;
#pragma unroll
    for (int i = ty; i < 32; i += 8)
        tile[i][tx] = W[(size_t)(k0 + i) * N + n0 + tx];
    __syncthreads();
#pragma unroll
    for (int i = ty; i < 32; i += 8)
        Wt[(size_t)(n0 + i) * K + k0 + tx] = f2bf(tile[tx][i]);
}

// ---------------------------------------------------------------------------
// Q-GEMM, 128x64 tile, BK=64 (R8 proven): C = cscale*(A[4096x1024] @ Bt^T),
// Bt [2048][1024], C bf16 ldc=2048. grid (32, 32) = 1024 blocks = 4/CU.
// Twin K=32 sub-tiles per barrier pair -> 16 MFMA / 2 barriers. LDS 24KB.
// ---------------------------------------------------------------------------
__global__ __launch_bounds__(256) void gemm_q(
    const ushort* __restrict__ A, const ushort* __restrict__ Bt,
    ushort* __restrict__ C, float cscale)
{
    __shared__ ushort As0[128 * 32];
    __shared__ ushort As1[128 * 32];
    __shared__ ushort Bs0[64 * 32];
    __shared__ ushort Bs1[64 * 32];
    const int t = threadIdx.x;
    const int lane = t & 63, w = t >> 6;
    const int q = lane >> 4, li = lane & 15;
    const int rowA = blockIdx.x * 128, colB = blockIdx.y * 64;
    const int ar = rowA + w * 32 + (lane >> 2);
    const int br = colB + w * 16 + (lane >> 2);
    const int cl = (lane & 3) * 8;
    ushort* adst0 = &As0[w * 32 * 32];
    ushort* adst1 = &As1[w * 32 * 32];
    ushort* bdst0 = &Bs0[w * 16 * 32];
    ushort* bdst1 = &Bs1[w * 16 * 32];

    floatx4 acc[2][4];
    const floatx4 z4 = {0.f, 0.f, 0.f, 0.f};
#pragma unroll
    for (int i = 0; i < 2; i++)
#pragma unroll
        for (int j = 0; j < 4; j++) acc[i][j] = z4;

    for (int k0 = 0; k0 < 1024; k0 += 64) {
        gl_lds16(A + (size_t)ar * 1024 + k0 + cl, adst0);
        gl_lds16(A + (size_t)(ar + 16) * 1024 + k0 + cl, adst0 + 16 * 32);
        gl_lds16(A + (size_t)ar * 1024 + k0 + 32 + cl, adst1);
        gl_lds16(A + (size_t)(ar + 16) * 1024 + k0 + 32 + cl, adst1 + 16 * 32);
        gl_lds16(Bt + (size_t)br * 1024 + k0 + cl, bdst0);
        gl_lds16(Bt + (size_t)br * 1024 + k0 + 32 + cl, bdst1);
        __syncthreads();
        short8 af[2], bf[4];
#pragma unroll
        for (int i = 0; i < 2; i++) af[i] = *(const short8*)&As0[(w * 32 + i * 16 + li) * 32 + q * 8];
#pragma unroll
        for (int j = 0; j < 4; j++) bf[j] = *(const short8*)&Bs0[(j * 16 + li) * 32 + q * 8];
#pragma unroll
        for (int i = 0; i < 2; i++)
#pragma unroll
            for (int j = 0; j < 4; j++)
                acc[i][j] = __builtin_amdgcn_mfma_f32_16x16x32_bf16(af[i], bf[j], acc[i][j], 0, 0, 0);
#pragma unroll
        for (int i = 0; i < 2; i++) af[i] = *(const short8*)&As1[(w * 32 + i * 16 + li) * 32 + q * 8];
#pragma unroll
        for (int j = 0; j < 4; j++) bf[j] = *(const short8*)&Bs1[(j * 16 + li) * 32 + q * 8];
#pragma unroll
        for (int i = 0; i < 2; i++)
#pragma unroll
            for (int j = 0; j < 4; j++)
                acc[i][j] = __builtin_amdgcn_mfma_f32_16x16x32_bf16(af[i], bf[j], acc[i][j], 0, 0, 0);
        __syncthreads();
    }
#pragma unroll
    for (int i = 0; i < 2; i++) {
        const int rowb = rowA + w * 32 + i * 16 + q * 4;
#pragma unroll
        for (int j = 0; j < 4; j++) {
            const int col = colB + j * 16 + li;
#pragma unroll
            for (int r = 0; r < 4; r++)
                C[(size_t)(rowb + r) * 2048 + col] = f2bf(acc[i][j][r] * cscale);
        }
    }
}

// ---------------------------------------------------------------------------
// KV-GEMM (z=2 batched): C = A[4096x1024] @ Bt[128][1024]^T; epilogue splits
// cols 0-63 -> Kp[row*64+col], 64-127 -> Vt[b][d][tok]. grid (32,1,2).
// ---------------------------------------------------------------------------
__global__ __launch_bounds__(256) void gemm_kv(
    const ushort* __restrict__ A0, const ushort* __restrict__ A1,
    const ushort* __restrict__ B0, const ushort* __restrict__ B1,
    ushort* __restrict__ C0, ushort* __restrict__ C1,
    ushort* __restrict__ vt0, ushort* __restrict__ vt1)
{
    __shared__ ushort As[128 * 32];
    __shared__ ushort Bs[128 * 32];
    const int z = blockIdx.z;
    const ushort* A = z ? A1 : A0;
    const ushort* Bt = z ? B1 : B0;
    ushort* Kp = z ? C1 : C0;
    ushort* vt = z ? vt1 : vt0;

    const int t = threadIdx.x;
    const int lane = t & 63, w = t >> 6;
    const int q = lane >> 4, li = lane & 15;
    const int wr = (w >> 1) * 64, wc = (w & 1) * 64;
    const int rowA = blockIdx.x * 128;
    const int ar = rowA + w * 32 + (lane >> 2);
    const int br = w * 32 + (lane >> 2);
    const int cl = (lane & 3) * 8;
    ushort* adst = &As[w * 32 * 32];
    ushort* bdst = &Bs[w * 32 * 32];

    floatx4 acc[4][4];
    const floatx4 z4 = {0.f, 0.f, 0.f, 0.f};
#pragma unroll
    for (int i = 0; i < 4; i++)
#pragma unroll
        for (int j = 0; j < 4; j++) acc[i][j] = z4;

    for (int k0 = 0; k0 < 1024; k0 += 32) {
        gl_lds16(A + (size_t)ar * 1024 + k0 + cl, adst);
        gl_lds16(A + (size_t)(ar + 16) * 1024 + k0 + cl, adst + 16 * 32);
        gl_lds16(Bt + (size_t)br * 1024 + k0 + cl, bdst);
        gl_lds16(Bt + (size_t)(br + 16) * 1024 + k0 + cl, bdst + 16 * 32);
        __syncthreads();
        short8 af[4], bf[4];
#pragma unroll
        for (int i = 0; i < 4; i++) af[i] = *(const short8*)&As[(wr + i * 16 + li) * 32 + q * 8];
#pragma unroll
        for (int j = 0; j < 4; j++) bf[j] = *(const short8*)&Bs[(wc + j * 16 + li) * 32 + q * 8];
#pragma unroll
        for (int i = 0; i < 4; i++)
#pragma unroll
            for (int j = 0; j < 4; j++)
                acc[i][j] = __builtin_amdgcn_mfma_f32_16x16x32_bf16(af[i], bf[j], acc[i][j], 0, 0, 0);
        __syncthreads();
    }
#pragma unroll
    for (int i = 0; i < 4; i++) {
        const int rowb = rowA + wr + i * 16 + q * 4;
#pragma unroll
        for (int j = 0; j < 4; j++) {
            const int col = wc + j * 16 + li;
#pragma unroll
            for (int r = 0; r < 4; r++) {
                const int row = rowb + r;
                const ushort vb = f2bf(acc[i][j][r]);
                if (col < 64) Kp[(size_t)row * 64 + col] = vb;
                else vt[((row >> 10) << 16) + ((col - 64) << 10) + (row & 1023)] = vb;
            }
        }
    }
}

// ---------------------------------------------------------------------------
// Fused concat-projection GEMM, 128x64 tile, BK=64 (R8 proven), K=2048:
// C = [A1|A2] @ Bt^T + bias (fp32 out). grid (32, 16) = 512 blocks = 2/CU.
// ---------------------------------------------------------------------------
__global__ __launch_bounds__(256) void gemm_proj(
    const ushort* __restrict__ A1, const ushort* __restrict__ A2,
    const ushort* __restrict__ Bt, const float* __restrict__ bias,
    float* __restrict__ C)
{
    __shared__ ushort As0[128 * 32];
    __shared__ ushort As1[128 * 32];
    __shared__ ushort Bs0[64 * 32];
    __shared__ ushort Bs1[64 * 32];
    const int t = threadIdx.x;
    const int lane = t & 63, w = t >> 6;
    const int q = lane >> 4, li = lane & 15;
    const int rowA = blockIdx.x * 128, colB = blockIdx.y * 64;
    const int ar = rowA + w * 32 + (lane >> 2);
    const int br = colB + w * 16 + (lane >> 2);
    const int cl = (lane & 3) * 8;
    ushort* adst0 = &As0[w * 32 * 32];
    ushort* adst1 = &As1[w * 32 * 32];
    ushort* bdst0 = &Bs0[w * 16 * 32];
    ushort* bdst1 = &Bs1[w * 16 * 32];

    floatx4 acc[2][4];
    const floatx4 z4 = {0.f, 0.f, 0.f, 0.f};
#pragma unroll
    for (int i = 0; i < 2; i++)
#pragma unroll
        for (int j = 0; j < 4; j++) acc[i][j] = z4;

    for (int k0 = 0; k0 < 2048; k0 += 64) {
        const ushort* Ap = (k0 < 1024) ? A1 : A2;
        const int kc = k0 & 1023;
        const int kp0 = kc + cl;
        const int kp1 = kc + 32 + cl;
        const int koff = (k0 >= 1024) ? 64 : 0;
        const int ks0 = ((kp0 >> 6) << 7) + (kp0 & 63) + koff;
        const int ks1 = ((kp1 >> 6) << 7) + (kp1 & 63) + koff;
        gl_lds16(Ap + (size_t)ar * 1024 + kc + cl, adst0);
        gl_lds16(Ap + (size_t)(ar + 16) * 1024 + kc + cl, adst0 + 16 * 32);
        gl_lds16(Ap + (size_t)ar * 1024 + kc + 32 + cl, adst1);
        gl_lds16(Ap + (size_t)(ar + 16) * 1024 + kc + 32 + cl, adst1 + 16 * 32);
        gl_lds16(Bt + (size_t)br * 2048 + ks0, bdst0);
        gl_lds16(Bt + (size_t)br * 2048 + ks1, bdst1);
        __syncthreads();
        short8 af[2], bf[4];
#pragma unroll
        for (int i = 0; i < 2; i++) af[i] = *(const short8*)&As0[(w * 32 + i * 16 + li) * 32 + q * 8];
#pragma unroll
        for (int j = 0; j < 4; j++) bf[j] = *(const short8*)&Bs0[(j * 16 + li) * 32 + q * 8];
#pragma unroll
        for (int i = 0; i < 2; i++)
#pragma unroll
            for (int j = 0; j < 4; j++)
                acc[i][j] = __builtin_amdgcn_mfma_f32_16x16x32_bf16(af[i], bf[j], acc[i][j], 0, 0, 0);
#pragma unroll
        for (int i = 0; i < 2; i++) af[i] = *(const short8*)&As1[(w * 32 + i * 16 + li) * 32 + q * 8];
#pragma unroll
        for (int j = 0; j < 4; j++) bf[j] = *(const short8*)&Bs1[(j * 16 + li) * 32 + q * 8];
#pragma unroll
        for (int i = 0; i < 2; i++)
#pragma unroll
            for (int j = 0; j < 4; j++)
                acc[i][j] = __builtin_amdgcn_mfma_f32_16x16x32_bf16(af[i], bf[j], acc[i][j], 0, 0, 0);
        __syncthreads();
    }
#pragma unroll
    for (int i = 0; i < 2; i++) {
        const int rowb = rowA + w * 32 + i * 16 + q * 4;
#pragma unroll
        for (int j = 0; j < 4; j++) {
            const int col = colB + j * 16 + li;
            const float bv = bias[col];
#pragma unroll
            for (int r = 0; r < 4; r++)
                C[(size_t)(rowb + r) * 1024 + col] = acc[i][j][r] + bv;
        }
    }
}

// ---------------------------------------------------------------------------
// Flash attention v10: v9 + interleaved S0/S1 chains. The two ktiles' QK^T
// MFMAs issue alternately (independent accumulators -> 2 chains in the MFMA
// pipe); S1 stays live through ktile0's exp/pack/PV so VALU overlaps the
// S1 chain tail. lsum via ones-MFMA (same C-layout). grid (8,16,8).
// ---------------------------------------------------------------------------
__global__ __launch_bounds__(256, 4) void attn_kernel(
    const ushort* __restrict__ Qbase,
    const ushort* __restrict__ KVa, const ushort* __restrict__ KVb,
    ushort* __restrict__ OutA, ushort* __restrict__ OutB)
{
    __shared__ ushort Kt[2][64 * 68];   // [buf][key][d]
    __shared__ ushort Vt[2][64 * 68];   // [buf][d][key]

    const int t = threadIdx.x;
    const int lane = t & 63, w = t >> 6;
    const int ql = lane & 31, hi = lane >> 5;
    const int qt = blockIdx.x, h = blockIdx.y;
    const int z = blockIdx.z, b = z >> 1, a2 = z & 1;

    const ushort* Q  = Qbase + (a2 ? 1024 : 0);
    const ushort* KV = a2 ? KVb : KVa;
    ushort* Out      = a2 ? OutB : OutA;
    const ushort* Kp = KV;
    const ushort* Vg = KV + 262144;

    const size_t qrow = (size_t)(b * 1024 + qt * 128 + w * 32 + ql);
    short8 qf[4];
#pragma unroll
    for (int dc = 0; dc < 4; dc++)
        qf[dc] = *(const short8*)&Q[qrow * 2048 + h * 64 + dc * 16 + hi * 8];

    floatx16 accO[2], accO2;
#pragma unroll
    for (int dt = 0; dt < 2; dt++)
#pragma unroll
        for (int i = 0; i < 16; i++) accO[dt][i] = 0.f;
#pragma unroll
    for (int i = 0; i < 16; i++) accO2[i] = 0.f;

    // bf16 1.0 broadcast B-operand (constant -> fragment-layout irrelevant)
    short8 one8;
#pragma unroll
    for (int i = 0; i < 8; i++) one8[i] = (short)0x3F80;

    const int srow = t >> 2, sch = (t & 3) * 16;
    const ushort* ksrc0 = &Kp[(size_t)(b * 1024 + srow) * 64 + sch];
    const ushort* vsrc0 = &Vg[(size_t)(b * 64 + srow) * 1024 + sch];
    const int soff = srow * 68 + sch;

    short8 kreg[2], vreg[2];
    // prologue: tile 0 -> regs -> buf0; tile 1 -> regs
#pragma unroll
    for (int i = 0; i < 2; i++) {
        kreg[i] = *(const short8*)&ksrc0[i * 8];
        vreg[i] = *(const short8*)&vsrc0[i * 8];
    }
#pragma unroll
    for (int i = 0; i < 2; i++) {
        *(short8*)&Kt[0][soff + i * 8] = kreg[i];
        *(short8*)&Vt[0][soff + i * 8] = vreg[i];
    }
#pragma unroll
    for (int i = 0; i < 2; i++) {
        kreg[i] = *(const short8*)&ksrc0[64 * 64 + i * 8];
        vreg[i] = *(const short8*)&vsrc0[64 + i * 8];
    }

    for (int kt = 0; kt < 16; kt++) {
        const int cur = kt & 1;
        __syncthreads();   // buf[cur] writes visible; buf[cur^1] readers done

        // unconditional: write tile kt+1 into buf[cur^1]
        // (kt=15: rewrites tile-15 data into the dead buffer — never read)
#pragma unroll
        for (int i = 0; i < 2; i++) {
            *(short8*)&Kt[cur ^ 1][soff + i * 8] = kreg[i];
            *(short8*)&Vt[cur ^ 1][soff + i * 8] = vreg[i];
        }
        // unconditional clamped prefetch of tile min(kt+2,15); values of the
        // clamped iterations are never consumed (branch-free -> no spills)
        {
            const int nt = (kt + 2 > 15) ? 15 : (kt + 2);
            const ushort* ksrc = ksrc0 + (size_t)nt * 64 * 64;
            const ushort* vsrc = vsrc0 + nt * 64;
#pragma unroll
            for (int i = 0; i < 2; i++) {
                kreg[i] = *(const short8*)&ksrc[i * 8];
                vreg[i] = *(const short8*)&vsrc[i * 8];
            }
        }

        // --- interleaved S0/S1: two independent MFMA chains ---
        floatx16 S0, S1;
#pragma unroll
        for (int i = 0; i < 16; i++) { S0[i] = 0.f; S1[i] = 0.f; }
        __builtin_amdgcn_s_setprio(1);
#pragma unroll
        for (int dc = 0; dc < 4; dc++) {
            short8 kf0 = *(const short8*)&Kt[cur][(ql) * 68 + dc * 16 + hi * 8];
            short8 kf1 = *(const short8*)&Kt[cur][(32 + ql) * 68 + dc * 16 + hi * 8];
            S0 = __builtin_amdgcn_mfma_f32_32x32x16_bf16(kf0, qf[dc], S0, 0, 0, 0);
            S1 = __builtin_amdgcn_mfma_f32_32x32x16_bf16(kf1, qf[dc], S1, 0, 0, 0);
        }
        __builtin_amdgcn_s_setprio(0);

#pragma unroll
        for (int ktile = 0; ktile < 2; ktile++) {
            const floatx16& S = ktile ? S1 : S0;
            float e[16];
#pragma unroll
            for (int r = 0; r < 16; r++) e[r] = __expf(S[r]);

#pragma unroll
            for (int p = 0; p < 2; p++) {
                unsigned cA = cvt_pk_bf16(e[8 * p + 0], e[8 * p + 1]);
                unsigned cC = cvt_pk_bf16(e[8 * p + 2], e[8 * p + 3]);
                unsigned cB = cvt_pk_bf16(e[8 * p + 4], e[8 * p + 5]);
                unsigned cD = cvt_pk_bf16(e[8 * p + 6], e[8 * p + 7]);
                uintx2 s02 = __builtin_amdgcn_permlane32_swap(cA, cB, false, false);
                uintx2 s13 = __builtin_amdgcn_permlane32_swap(cC, cD, false, false);
                union { unsigned u[4]; short8 s; } pf;
                pf.u[0] = s02[0]; pf.u[1] = s13[0];
                pf.u[2] = s02[1]; pf.u[3] = s13[1];
                const int kslot = ktile * 2 + p;
                __builtin_amdgcn_s_setprio(1);
#pragma unroll
                for (int dt = 0; dt < 2; dt++) {
                    short8 vf = *(const short8*)&Vt[cur][(dt * 32 + ql) * 68 + kslot * 16 + hi * 8];
                    accO[dt] = __builtin_amdgcn_mfma_f32_32x32x16_bf16(pf.s, vf, accO[dt], 0, 0, 0);
                }
                // lsum: row-sums of P, same C-layout as accO (ones B-operand)
                accO2 = __builtin_amdgcn_mfma_f32_32x32x16_bf16(pf.s, one8, accO2, 0, 0, 0);
                __builtin_amdgcn_s_setprio(0);
            }
        }
        // no end-of-iter barrier: next top-barrier separates buffer roles
    }

    const int orow0 = b * 1024 + qt * 128 + w * 32;
#pragma unroll
    for (int g = 0; g < 4; g++) {
#pragma unroll
        for (int rr = 0; rr < 4; rr++) {
            const float inv = 1.f / accO2[g * 4 + rr];   // same-lane lsum
            const int row = orow0 + g * 8 + hi * 4 + rr;
#pragma unroll
            for (int dt = 0; dt < 2; dt++)
                Out[(size_t)row * 1024 + h * 64 + dt * 32 + ql] =
                    f2bf(accO[dt][g * 4 + rr] * inv);
        }
    }
}

// ---------------------------------------------------------------------------
extern "C" void kernel_launch(void* const* d_in, const int* in_sizes, int n_in,
                              void* d_out, int out_size, void* d_ws, size_t ws_size,
                              hipStream_t stream) {
    const float* qx    = (const float*)d_in[0];
    const float* kvx   = (const float*)d_in[1];
    const float* qs    = (const float*)d_in[2];
    const float* kvs   = (const float*)d_in[3];
    const float* w_qx1 = (const float*)d_in[4];
    const float* w_qs1 = (const float*)d_in[5];
    const float* w_qx2 = (const float*)d_in[6];
    const float* w_qs2 = (const float*)d_in[7];
    const float* w_kvx = (const float*)d_in[8];
    const float* w_kvs = (const float*)d_in[9];
    const float* w_xp  = (const float*)d_in[10];
    const float* b_xp  = (const float*)d_in[11];
    const float* w_sp  = (const float*)d_in[12];
    const float* b_sp  = (const float*)d_in[13];
    float* out = (float*)d_out;
    (void)ws_size; (void)in_sizes; (void)n_in; (void)out_size;

    ushort* ws   = (ushort*)d_ws;
    ushort* Wb   = ws;
    ushort* q1q2 = ws + 4194304;
    ushort* Mbuf = ws + 12582912;
    ushort* kvpx = ws + 16777216;
    ushort* kvps = ws + 17301504;

    // 1) cast kv activations: kvx_b -> Mbuf, kvs_b -> q1q2 (both dead regions)
    CB c1; c1.src[0] = kvx; c1.dst[0] = Mbuf; c1.src[1] = kvs; c1.dst[1] = q1q2;
    castb<<<dim3(4096, 1, 2), 256, 0, stream>>>(c1);

    // 2) transpose kv + s-path Q weights into Wb
    TB tb1;
    tb1.src[0] = w_kvx; tb1.dst[0] = Wb;           tb1.K[0] = 1024; tb1.N[0] = 128;
    tb1.src[1] = w_kvs; tb1.dst[1] = Wb + 131072;  tb1.K[1] = 1024; tb1.N[1] = 128;
    tb1.src[2] = w_qs1; tb1.dst[2] = Wb + 262144;  tb1.K[2] = 1024; tb1.N[2] = 1024;
    tb1.src[3] = w_qs2; tb1.dst[3] = Wb + 1310720; tb1.K[3] = 1024; tb1.N[3] = 1024;
    tbatch<<<dim3(32, 32, 4), 256, 0, stream>>>(tb1);

    // 3) kv projections (z=2): K->Kp, V->Vt
    gemm_kv<<<dim3(32, 1, 2), 256, 0, stream>>>(
        Mbuf, q1q2, Wb, Wb + 131072, kvpx, kvps, kvpx + 262144, kvps + 262144);

    // 4) cast qs -> Mbuf (kvx_b dead)
    CB c2; c2.src[0] = qs; c2.dst[0] = Mbuf; c2.src[1] = qs; c2.dst[1] = Mbuf;
    castb<<<dim3(4096, 1, 1), 256, 0, stream>>>(c2);

    // 5) s-path Q GEMM: q1s|q2s -> q1q2 (kvs_b dead), scale 1/8 folded
    gemm_q<<<dim3(32, 32), 256, 0, stream>>>(Mbuf, Wb + 262144, q1q2, 0.125f);

    // 6) s attention: M_s -> Mbuf (qs_b dead), M_sx -> d_out lo (bf16 scratch)
    attn_kernel<<<dim3(8, 16, 8), 256, 0, stream>>>(q1q2, kvps, kvpx, Mbuf, (ushort*)out);

    // 7) transpose sp + x-path Q weights (Wt_kv/Wt_qs dead)
    TB tb2;
    tb2.src[0] = w_sp;  tb2.dst[0] = Wb;           tb2.K[0] = 2048; tb2.N[0] = 1024;
    tb2.src[1] = w_qx1; tb2.dst[1] = Wb + 2097152; tb2.K[1] = 1024; tb2.N[1] = 1024;
    tb2.src[2] = w_qx2; tb2.dst[2] = Wb + 3145728; tb2.K[2] = 1024; tb2.N[2] = 1024;
    tb2.src[3] = w_sp;  tb2.dst[3] = Wb;           tb2.K[3] = 0;    tb2.N[3] = 0;
    tbatch<<<dim3(64, 32, 3), 256, 0, stream>>>(tb2);

    // 8) s_out = [M_sx | M_s] @ Wsp^T + b_sp -> d_out hi (fp32)
    gemm_proj<<<dim3(32, 16), 256, 0, stream>>>((ushort*)out, Mbuf, Wb, b_sp, out + 4194304);

    // 9) cast qx -> Mbuf (M_s dead)
    CB c3; c3.src[0] = qx; c3.dst[0] = Mbuf; c3.src[1] = qx; c3.dst[1] = Mbuf;
    castb<<<dim3(4096, 1, 1), 256, 0, stream>>>(c3);

    // 10) x-path Q GEMM -> q1q2 (dead after s-attn)
    gemm_q<<<dim3(32, 32), 256, 0, stream>>>(Mbuf, Wb + 2097152, q1q2, 0.125f);

    // 11) x attention: M_x -> Mbuf (qx_b dead), M_xs -> Wb (weights dead)
    attn_kernel<<<dim3(8, 16, 8), 256, 0, stream>>>(q1q2, kvpx, kvps, Mbuf, Wb);

    // 12) transpose xp -> q1q2 (dead after x-attn)
    TB tb3;
    tb3.src[0] = w_xp; tb3.dst[0] = q1q2; tb3.K[0] = 2048; tb3.N[0] = 1024;
    tb3.src[1] = w_xp; tb3.dst[1] = q1q2; tb3.K[1] = 0;    tb3.N[1] = 0;
    tb3.src[2] = w_xp; tb3.dst[2] = q1q2; tb3.K[2] = 0;    tb3.N[2] = 0;
    tb3.src[3] = w_xp; tb3.dst[3] = q1q2; tb3.K[3] = 0;    tb3.N[3] = 0;
    tbatch<<<dim3(64, 32, 1), 256, 0, stream>>>(tb3);

    // 13) x_out = [M_xs | M_x] @ Wxp^T + b_xp -> d_out lo (M_sx scratch dead)
    gemm_proj<<<dim3(32, 16), 256, 0, stream>>>(Wb, Mbuf, q1q2, b_xp, out);
}